// Round 1
// baseline (1936.367 us; speedup 1.0000x reference)
//
#include <hip/hip_runtime.h>

#define W 128
#define H 64
#define HW 8192
#define NB 8
#define CFP 632                 // padded NHWC channel stride (629 -> 632, 16B-aligned)

typedef __attribute__((ext_vector_type(8))) short short8;
typedef __attribute__((ext_vector_type(4))) float floatx4;

__device__ __forceinline__ float leakyf(float v) { return v >= 0.f ? v : 0.1f * v; }

__device__ __forceinline__ unsigned short f2bf(float f) {
    unsigned u = __float_as_uint(f);
    u += 0x7FFF + ((u >> 16) & 1);          // RNE
    return (unsigned short)(u >> 16);
}
__device__ __forceinline__ float bf2f(unsigned short s) {
    return __uint_as_float((unsigned)s << 16);
}

// ---------------------------------------------------------------------------
// ConvTranspose2d k=4 s=2 p=1, Cout=2, small Cin (used for prev_flow, Cin=2)
// ---------------------------------------------------------------------------
__global__ void upconv2_kernel(const float* __restrict__ in, int Cin, int Hin, int Win,
                               const float* __restrict__ w, const float* __restrict__ bias,
                               float* __restrict__ out, long obs)
{
    const int x = threadIdx.x;
    const int y = blockIdx.x;
    const int b = blockIdx.y;

    const int p = (y + 1) & 1;
    const int kyA = p, kyB = p + 2;
    const int iyA = (y + 1 - kyA) >> 1;
    const int iyB = (y + 1 - kyB) >> 1;
    const bool vyA = (iyA >= 0) && (iyA < Hin);
    const bool vyB = (iyB >= 0) && (iyB < Hin);

    const int q = (x + 1) & 1;
    const int kxA = q, kxB = q + 2;
    const int ixA = (x + 1 - kxA) >> 1;
    const int ixB = (x + 1 - kxB) >> 1;
    const bool vxA = (ixA >= 0) && (ixA < Win);
    const bool vxB = (ixB >= 0) && (ixB < Win);

    const bool mAA = vyA && vxA, mAB = vyA && vxB, mBA = vyB && vxA, mBB = vyB && vxB;
    const int oAA = iyA * Win + ixA, oAB = iyA * Win + ixB;
    const int oBA = iyB * Win + ixA, oBB = iyB * Win + ixB;
    const int wAA = kyA * 4 + kxA, wAB = kyA * 4 + kxB;
    const int wBA = kyB * 4 + kxA, wBB = kyB * 4 + kxB;

    float acc0 = bias[0];
    float acc1 = bias[1];
    const long hwin = (long)Hin * Win;
    const float* ip = in + (long)b * Cin * hwin;
    const float* wp = w;
    for (int ci = 0; ci < Cin; ++ci, ip += hwin, wp += 32) {
        float vAA = mAA ? ip[oAA] : 0.f;
        float vAB = mAB ? ip[oAB] : 0.f;
        float vBA = mBA ? ip[oBA] : 0.f;
        float vBB = mBB ? ip[oBB] : 0.f;
        acc0 += vAA * wp[wAA] + vAB * wp[wAB] + vBA * wp[wBA] + vBB * wp[wBB];
        acc1 += vAA * wp[16 + wAA] + vAB * wp[16 + wAB] + vBA * wp[16 + wBA] + vBB * wp[16 + wBB];
    }
    long o = (long)b * obs + y * W + x;
    out[o]      = acc0;
    out[o + HW] = acc1;
}

// ---------------------------------------------------------------------------
// Same transpose-conv, Cin split 8 ways within a 1024-thread block (latency fix
// for Cin=661). LDS reduce; s==0 group adds bias and stores.
// ---------------------------------------------------------------------------
__global__ __launch_bounds__(1024) void upconv2_split_kernel(
    const float* __restrict__ in, int Cin, int Hin, int Win,
    const float* __restrict__ w, const float* __restrict__ bias,
    float* __restrict__ out, long obs)
{
    __shared__ float red[8][128][2];

    const int x = threadIdx.x & 127;
    const int s = threadIdx.x >> 7;       // split 0..7 (wave-uniform)
    const int y = blockIdx.x;
    const int b = blockIdx.y;

    const int p = (y + 1) & 1;
    const int kyA = p, kyB = p + 2;
    const int iyA = (y + 1 - kyA) >> 1;
    const int iyB = (y + 1 - kyB) >> 1;
    const bool vyA = (iyA >= 0) && (iyA < Hin);
    const bool vyB = (iyB >= 0) && (iyB < Hin);

    const int q = (x + 1) & 1;
    const int kxA = q, kxB = q + 2;
    const int ixA = (x + 1 - kxA) >> 1;
    const int ixB = (x + 1 - kxB) >> 1;
    const bool vxA = (ixA >= 0) && (ixA < Win);
    const bool vxB = (ixB >= 0) && (ixB < Win);

    const bool mAA = vyA && vxA, mAB = vyA && vxB, mBA = vyB && vxA, mBB = vyB && vxB;
    const int oAA = iyA * Win + ixA, oAB = iyA * Win + ixB;
    const int oBA = iyB * Win + ixA, oBB = iyB * Win + ixB;
    const int wAA = kyA * 4 + kxA, wAB = kyA * 4 + kxB;
    const int wBA = kyB * 4 + kxA, wBB = kyB * 4 + kxB;

    const int per = (Cin + 7) / 8;
    const int lo = s * per;
    const int hi = min(lo + per, Cin);

    float acc0 = 0.f, acc1 = 0.f;
    const long hwin = (long)Hin * Win;
    const float* ip = in + (long)b * Cin * hwin + (long)lo * hwin;
    const float* wp = w + lo * 32;
    for (int ci = lo; ci < hi; ++ci, ip += hwin, wp += 32) {
        float vAA = mAA ? ip[oAA] : 0.f;
        float vAB = mAB ? ip[oAB] : 0.f;
        float vBA = mBA ? ip[oBA] : 0.f;
        float vBB = mBB ? ip[oBB] : 0.f;
        acc0 += vAA * wp[wAA] + vAB * wp[wAB] + vBA * wp[wBA] + vBB * wp[wBB];
        acc1 += vAA * wp[16 + wAA] + vAB * wp[16 + wAB] + vBA * wp[16 + wBA] + vBB * wp[16 + wBB];
    }
    red[s][x][0] = acc0;
    red[s][x][1] = acc1;
    __syncthreads();
    if (s == 0) {
        float a0 = bias[0], a1 = bias[1];
        #pragma unroll
        for (int t = 0; t < 8; ++t) { a0 += red[t][x][0]; a1 += red[t][x][1]; }
        long o = (long)b * obs + y * W + x;
        out[o]      = a0;
        out[o + HW] = a1;
    }
}

// ---------------------------------------------------------------------------
// Bilinear warp (zeros padding) -> warped_n NHWC bf16 (pitch 96).
// Block = 512 threads: 4 channel-splits x 128 px (one image row).
// LDS transpose so global stores are coalesced uint4.
// ---------------------------------------------------------------------------
__global__ __launch_bounds__(512) void warp_nhwc_kernel(
    const float* __restrict__ tenTwo, const float* __restrict__ flow4,
    unsigned short* __restrict__ warped_n)
{
    __shared__ unsigned short tile[128 * 98];   // pitch 98 shorts: conflict-free b16 stores

    const int x   = threadIdx.x & 127;
    const int sub = threadIdx.x >> 7;           // 0..3, 24 channels each
    const int row = blockIdx.x;                 // b*H + y
    const int b = row >> 6;
    const int y = row & 63;

    const long fb = (long)b * 2 * HW + y * W + x;
    const float px = (float)x + 1.25f * flow4[fb];
    const float py = (float)y + 1.25f * flow4[fb + HW];

    const float x0f = floorf(px), y0f = floorf(py);
    const float wx = px - x0f, wy = py - y0f;
    const int x0 = (int)x0f, y0 = (int)y0f;
    const int x1 = x0 + 1,   y1 = y0 + 1;

    const bool vx0 = (x0 >= 0) && (x0 < W), vx1 = (x1 >= 0) && (x1 < W);
    const bool vy0 = (y0 >= 0) && (y0 < H), vy1 = (y1 >= 0) && (y1 < H);
    const int cx0 = min(max(x0, 0), W - 1), cx1 = min(max(x1, 0), W - 1);
    const int cy0 = min(max(y0, 0), H - 1), cy1 = min(max(y1, 0), H - 1);

    const float w00 = (1.f - wy) * (1.f - wx) * ((vy0 && vx0) ? 1.f : 0.f);
    const float w01 = (1.f - wy) * wx         * ((vy0 && vx1) ? 1.f : 0.f);
    const float w10 = wy * (1.f - wx)         * ((vy1 && vx0) ? 1.f : 0.f);
    const float w11 = wy * wx                 * ((vy1 && vx1) ? 1.f : 0.f);

    const int o00 = cy0 * W + cx0, o01 = cy0 * W + cx1;
    const int o10 = cy1 * W + cx0, o11 = cy1 * W + cx1;

    for (int i = 0; i < 24; ++i) {
        const int c = sub * 24 + i;
        const float* pch = tenTwo + (long)(b * 96 + c) * HW;
        const float v = pch[o00] * w00 + pch[o01] * w01 + pch[o10] * w10 + pch[o11] * w11;
        tile[x * 98 + c] = f2bf(v);
    }
    __syncthreads();

    // write out 128 px x 96 ch = 1536 uint4
    unsigned short* op = warped_n + (long)row * 128 * 96;
    for (int u = threadIdx.x; u < 1536; u += 512) {
        const int pxi = u / 12;
        const int cc = u - pxi * 12;
        const unsigned short* tp = tile + pxi * 98 + cc * 8;
        uint4 v;
        v.x = *(const unsigned*)(tp + 0);
        v.y = *(const unsigned*)(tp + 2);
        v.z = *(const unsigned*)(tp + 4);
        v.w = *(const unsigned*)(tp + 6);
        *(uint4*)(op + u * 8) = v;
    }
}

// ---------------------------------------------------------------------------
// Cost volume from NHWC bf16 warped + NCHW fp32 tenOne (held in 96 VGPRs).
// Block = 512 threads: 4 tap-groups x 128 px (one row). Writes bf16 into
// featn channels 448..528 (with leaky).
// ---------------------------------------------------------------------------
__global__ __launch_bounds__(512) void corr_kernel(
    const float* __restrict__ tenOne, const unsigned short* __restrict__ warped_n,
    unsigned short* __restrict__ featn)
{
    const int x  = threadIdx.x & 127;
    const int kg = threadIdx.x >> 7;     // 0..3
    const int row = blockIdx.x;          // b*H + y
    const int b = row >> 6;
    const int y = row & 63;
    const long pix = (long)row * W + x;

    float one[96];
    const float* op = tenOne + (long)b * 96 * HW + y * W + x;
    #pragma unroll
    for (int j = 0; j < 96; ++j) one[j] = op[(long)j * HW];

    const int k0 = kg * 21;
    const int k1 = min(k0 + 21, 81);
    for (int k = k0; k < k1; ++k) {
        const int dy = k / 9 - 4, dx = k % 9 - 4;   // wave-uniform
        const int yy = y + dy, xx = x + dx;
        float acc = 0.f;
        if (yy >= 0 && yy < H && xx >= 0 && xx < W) {
            const unsigned short* wp = warped_n + ((long)(b * H + yy) * W + xx) * 96;
            #pragma unroll
            for (int c4 = 0; c4 < 12; ++c4) {
                const uint4 v = *(const uint4*)(wp + c4 * 8);
                unsigned uu[4] = {v.x, v.y, v.z, v.w};
                #pragma unroll
                for (int e = 0; e < 4; ++e) {
                    const float flo = __uint_as_float(uu[e] << 16);
                    const float fhi = __uint_as_float(uu[e] & 0xffff0000u);
                    acc += one[c4 * 8 + e * 2] * flo + one[c4 * 8 + e * 2 + 1] * fhi;
                }
            }
        }
        featn[pix * CFP + 448 + k] = f2bf(leakyf(acc * (1.f / 96.f)));
    }
}

// ---------------------------------------------------------------------------
// Pack tenOne/flow/upfeat (fp32) into featn bf16 channels 528..631.
// (528 is a placeholder overwritten later by corr; 629..631 are zero pad.)
// ---------------------------------------------------------------------------
__global__ void pack_kernel(const float* __restrict__ one, const float* __restrict__ flow4,
                            const float* __restrict__ up4, unsigned short* __restrict__ featn)
{
    const long t = (long)blockIdx.x * 256 + threadIdx.x;    // pixel 0..65535
    const long b = t >> 13;
    const long p = t & (HW - 1);
    unsigned short buf[8];
    for (int cc = 0; cc < 13; ++cc) {
        #pragma unroll
        for (int j = 0; j < 8; ++j) {
            const int c = 528 + cc * 8 + j;
            float v;
            if (c < 529)      v = 0.f;
            else if (c < 625) v = one[(b * 96 + (c - 529)) * HW + p];
            else if (c < 627) v = flow4[(b * 2 + (c - 625)) * HW + p];
            else if (c < 629) v = up4[(b * 2 + (c - 627)) * HW + p];
            else              v = 0.f;
            buf[j] = f2bf(v);
        }
        *(uint4*)(featn + t * CFP + 528 + cc * 8) = *(const uint4*)buf;
    }
}

// ---------------------------------------------------------------------------
// feat_nhwc bf16 -> d_out feat region fp32 NCHW (B,629,H,W)
// ---------------------------------------------------------------------------
__global__ void unpack_kernel(const unsigned short* __restrict__ featn, float* __restrict__ out)
{
    const long t = (long)blockIdx.x * 256 + threadIdx.x;    // pixel
    const long b = t >> 13;
    const long p = t & (HW - 1);
    const unsigned short* f = featn + t * CFP;
    float* ob = out + b * 629L * HW + p;
    for (int cc = 0; cc < 79; ++cc) {
        uint4 v = *(const uint4*)(f + cc * 8);
        unsigned short s[8];
        *(uint4*)s = v;
        #pragma unroll
        for (int j = 0; j < 8; ++j) {
            const int c = cc * 8 + j;
            if (c < 629) ob[(long)c * HW] = bf2f(s[j]);
        }
    }
}

// ---------------------------------------------------------------------------
// Weight convert: fp32 OIHW -> bf16 [co][tap][Kpad], zero-padded ci/co.
// ---------------------------------------------------------------------------
__global__ void wcvt_kernel(const float* __restrict__ w, unsigned short* __restrict__ wt,
                            int Cout, int Cin, int Kpad, long total)
{
    const long t = (long)blockIdx.x * 256 + threadIdx.x;
    if (t >= total) return;
    const int ci = (int)(t % Kpad);
    const long r = t / Kpad;
    const int tap = (int)(r % 9);
    const int co = (int)(r / 9);
    float v = 0.f;
    if (co < Cout && ci < Cin) v = w[((long)co * Cin + ci) * 9 + tap];
    wt[t] = f2bf(v);
}

// ---------------------------------------------------------------------------
// Implicit-GEMM 3x3 conv, bf16 MFMA 16x16x32, fp32 accum.
// R3: half-row blocks (64 px) -> grid 1024 (4 blocks/CU, ~50% occupancy cap)
//     + T14 reg-prefetch of next K-chunk so global latency hides under MFMA.
//     Each of 4 waves owns one 16-px M-tile x NF N-tiles.
// ---------------------------------------------------------------------------
template<int NF>
__global__ __launch_bounds__(256, 4) void conv_mfma(
    const unsigned short* __restrict__ featn, int c0, int Kpad,
    const unsigned short* __restrict__ wt, const float* __restrict__ bias,
    unsigned short* __restrict__ outf, int oc0, float* __restrict__ flowout)
{
    __shared__ unsigned short tile[3 * 66 * 40];   // [r*66+xx][ch pad 40], 15.8 KB

    const int half = blockIdx.x;         // 0..1 -> x half-row
    const int row  = blockIdx.y;         // b*H + y
    const int b = row >> 6;
    const int y = row & 63;
    const int x0 = half << 6;
    const int tid = threadIdx.x;
    const int lane = tid & 63;
    const int wv = tid >> 6;             // wave -> 16-px m-tile
    const int l15 = lane & 15;
    const int q = lane >> 4;

    // Precompute per-thread staging descriptors: 792 uint4 units
    // (3 rows x 66 px x 4 subs of 16B = 32 ch) spread over 256 threads.
    long gofs[4];
    int  lofs[4];
    bool gval[4];
    #pragma unroll
    for (int it = 0; it < 4; ++it) {
        const int u = tid + it * 256;
        const int pr = u >> 2;           // pixel unit 0..197
        const int sub = u & 3;
        const int r = (pr >= 132) ? 2 : (pr >= 66 ? 1 : 0);
        const int xx = pr - r * 66;
        const int gy = y + r - 1, gx = x0 + xx - 1;
        const bool inb = (u < 792) && (gy >= 0) && (gy < H) && (gx >= 0) && (gx < W);
        gval[it] = inb;
        gofs[it] = inb ? (((long)(b * H + gy) * W + gx) * CFP + c0 + sub * 8) : 0;
        lofs[it] = (u < 792) ? (pr * 40 + sub * 8) : -1;
    }

    floatx4 acc[NF];
    #pragma unroll
    for (int nf = 0; nf < NF; ++nf) acc[nf] = (floatx4){0.f, 0.f, 0.f, 0.f};

    const int wstride = 9 * Kpad;
    const int nchunks = Kpad >> 5;

    // prefetch chunk 0 into registers
    uint4 rg[4];
    #pragma unroll
    for (int it = 0; it < 4; ++it)
        rg[it] = gval[it] ? *(const uint4*)(featn + gofs[it]) : make_uint4(0u, 0u, 0u, 0u);

    for (int kc = 0; kc < nchunks; ++kc) {
        if (kc) __syncthreads();                   // prev compute done before overwrite
        #pragma unroll
        for (int it = 0; it < 4; ++it)
            if (lofs[it] >= 0) *(uint4*)&tile[lofs[it]] = rg[it];
        __syncthreads();

        // issue next chunk's loads BEFORE the MFMA phase (latency hides under it;
        // vmcnt waits land at next iteration's ds_write)
        if (kc + 1 < nchunks) {
            #pragma unroll
            for (int it = 0; it < 4; ++it)
                rg[it] = gval[it] ? *(const uint4*)(featn + gofs[it] + (kc + 1) * 32)
                                  : make_uint4(0u, 0u, 0u, 0u);
        }

        #pragma unroll
        for (int ky = 0; ky < 3; ++ky) {
            #pragma unroll
            for (int kx = 0; kx < 3; ++kx) {
                const int tap = ky * 3 + kx;
                const short8 a0 = *(const short8*)&tile[(ky * 66 + wv * 16 + l15 + kx) * 40 + q * 8];
                const unsigned short* wb = wt + (long)l15 * wstride + tap * Kpad + kc * 32 + q * 8;
                #pragma unroll
                for (int nf = 0; nf < NF; ++nf) {
                    const short8 bf = *(const short8*)(wb + (long)nf * 16 * wstride);
                    acc[nf] = __builtin_amdgcn_mfma_f32_16x16x32_bf16(a0, bf, acc[nf], 0, 0, 0);
                }
            }
        }
    }

    const int xb = x0 + wv * 16 + q * 4;
    if (flowout == nullptr) {
        float bv[NF];
        #pragma unroll
        for (int nf = 0; nf < NF; ++nf) bv[nf] = bias[nf * 16 + l15];
        #pragma unroll
        for (int r = 0; r < 4; ++r) {
            const long pixo = (long)row * W + xb + r;
            #pragma unroll
            for (int nf = 0; nf < NF; ++nf) {
                float v = acc[nf][r] + bv[nf];
                outf[pixo * CFP + oc0 + nf * 16 + l15] = f2bf(leakyf(v));
            }
        }
    } else {
        if (l15 < 2) {
            const float bb = bias[l15];
            #pragma unroll
            for (int r = 0; r < 4; ++r) {
                float v = acc[0][r] + bb;
                flowout[((long)b * 2 + l15) * HW + y * W + xb + r] = leakyf(v);
            }
        }
    }
}

// ---------------------------------------------------------------------------
extern "C" void kernel_launch(void* const* d_in, const int* in_sizes, int n_in,
                              void* d_out, int out_size, void* d_ws, size_t ws_size,
                              hipStream_t stream)
{
    const float* tenOne    = (const float*)d_in[0];
    const float* tenTwo    = (const float*)d_in[1];
    const float* prev_flow = (const float*)d_in[2];
    const float* prev_feat = (const float*)d_in[3];
    const float* w_upflow  = (const float*)d_in[4];
    const float* b_upflow  = (const float*)d_in[5];
    const float* w_upfeat  = (const float*)d_in[6];
    const float* b_upfeat  = (const float*)d_in[7];
    const float* wc[6] = {(const float*)d_in[8],  (const float*)d_in[10], (const float*)d_in[12],
                          (const float*)d_in[14], (const float*)d_in[16], (const float*)d_in[18]};
    const float* bc[6] = {(const float*)d_in[9],  (const float*)d_in[11], (const float*)d_in[13],
                          (const float*)d_in[15], (const float*)d_in[17], (const float*)d_in[19]};

    float* flow_out = (float*)d_out;                  // (B,2,H,W)
    float* feat_out = flow_out + (long)NB * 2 * HW;   // (B,629,H,W)

    // workspace layout (bytes)
    char* ws = (char*)d_ws;
    unsigned short* featn    = (unsigned short*)ws;                 // 82,837,504 (+slack)
    unsigned short* warped_n = (unsigned short*)(ws + 82841600L);   // 12,582,912
    float* flow4 = (float*)(ws + 95424512L);                        // 524,288
    float* up4   = (float*)(ws + 95948800L);                        // 524,288
    unsigned short* wt1 = (unsigned short*)(ws + 96473088L);
    unsigned short* wt2 = (unsigned short*)(ws + 96915456L);
    unsigned short* wt3 = (unsigned short*)(ws + 97652736L);
    unsigned short* wt4 = (unsigned short*)(ws + 98426880L);
    unsigned short* wt5 = (unsigned short*)(ws + 99053568L);
    unsigned short* wt6 = (unsigned short*)(ws + 99403776L);
    unsigned short* wts[6] = {wt1, wt2, wt3, wt4, wt5, wt6};

    const int Cout[6] = {128, 128, 96, 64, 32, 2};
    const int Cin [6] = {181, 309, 437, 533, 597, 629};
    const int Kpad[6] = {192, 320, 448, 544, 608, 640};
    const int CoPd[6] = {128, 128, 96, 64, 32, 16};
    const int c0  [6] = {448, 320, 192, 96, 32, 0};
    const int oc0 [6] = {320, 192, 96, 32, 0, 0};

    for (int i = 0; i < 6; ++i) {
        long total = (long)CoPd[i] * 9 * Kpad[i];
        wcvt_kernel<<<(int)((total + 255) / 256), 256, 0, stream>>>(
            wc[i], wts[i], Cout[i], Cin[i], Kpad[i], total);
    }

    // upsample flow (small) + feat (split-reduce)
    upconv2_kernel<<<dim3(H, NB), W, 0, stream>>>(prev_flow, 2, 32, 64,
                                                  w_upflow, b_upflow, flow4, (long)(2 * HW));
    upconv2_split_kernel<<<dim3(H, NB), 1024, 0, stream>>>(prev_feat, 661, 32, 64,
                                                           w_upfeat, b_upfeat, up4, (long)(2 * HW));

    // pack static channels, warp, correlation
    pack_kernel<<<256, 256, 0, stream>>>(tenOne, flow4, up4, featn);
    warp_nhwc_kernel<<<512, 512, 0, stream>>>(tenTwo, flow4, warped_n);
    corr_kernel<<<512, 512, 0, stream>>>(tenOne, warped_n, featn);

    // conv chain (MFMA), half-row blocks: grid (2, B*H)
    conv_mfma<8><<<dim3(2, 512), 256, 0, stream>>>(featn, c0[0], Kpad[0], wts[0], bc[0], featn, oc0[0], nullptr);
    conv_mfma<8><<<dim3(2, 512), 256, 0, stream>>>(featn, c0[1], Kpad[1], wts[1], bc[1], featn, oc0[1], nullptr);
    conv_mfma<6><<<dim3(2, 512), 256, 0, stream>>>(featn, c0[2], Kpad[2], wts[2], bc[2], featn, oc0[2], nullptr);
    conv_mfma<4><<<dim3(2, 512), 256, 0, stream>>>(featn, c0[3], Kpad[3], wts[3], bc[3], featn, oc0[3], nullptr);
    conv_mfma<2><<<dim3(2, 512), 256, 0, stream>>>(featn, c0[4], Kpad[4], wts[4], bc[4], featn, oc0[4], nullptr);
    conv_mfma<1><<<dim3(2, 512), 256, 0, stream>>>(featn, c0[5], Kpad[5], wts[5], bc[5], featn, 0, flow_out);

    // unpack feat to fp32 NCHW output
    unpack_kernel<<<256, 256, 0, stream>>>(featn, feat_out);
}

// Round 2
// 1168.139 us; speedup vs baseline: 1.6577x; 1.6577x over previous
//
#include <hip/hip_runtime.h>

#define W 128
#define H 64
#define HW 8192
#define NB 8
#define NPIX 65536              // NB*HW
#define CHSZ 2097152L           // shorts per channel-chunk: NPIX*32

typedef __attribute__((ext_vector_type(8))) short short8;
typedef __attribute__((ext_vector_type(4))) float floatx4;

__device__ __forceinline__ float leakyf(float v) { return v >= 0.f ? v : 0.1f * v; }

__device__ __forceinline__ unsigned short f2bf(float f) {
    unsigned u = __float_as_uint(f);
    u += 0x7FFF + ((u >> 16) & 1);          // RNE
    return (unsigned short)(u >> 16);
}
__device__ __forceinline__ float bf2f(unsigned short s) {
    return __uint_as_float((unsigned)s << 16);
}

// featn layout: chunked-channel NHWC. addr(c, pix) = ((c>>5)*NPIX + pix)*32 + (c&31)
// chunks 0..19 cover channels 0..639 (629 real + zero pad).

// ---------------------------------------------------------------------------
// ConvTranspose2d k=4 s=2 p=1, Cout=2, small Cin (used for prev_flow, Cin=2)
// ---------------------------------------------------------------------------
__global__ void upconv2_kernel(const float* __restrict__ in, int Cin, int Hin, int Win,
                               const float* __restrict__ w, const float* __restrict__ bias,
                               float* __restrict__ out, long obs)
{
    const int x = threadIdx.x;
    const int y = blockIdx.x;
    const int b = blockIdx.y;

    const int p = (y + 1) & 1;
    const int kyA = p, kyB = p + 2;
    const int iyA = (y + 1 - kyA) >> 1;
    const int iyB = (y + 1 - kyB) >> 1;
    const bool vyA = (iyA >= 0) && (iyA < Hin);
    const bool vyB = (iyB >= 0) && (iyB < Hin);

    const int q = (x + 1) & 1;
    const int kxA = q, kxB = q + 2;
    const int ixA = (x + 1 - kxA) >> 1;
    const int ixB = (x + 1 - kxB) >> 1;
    const bool vxA = (ixA >= 0) && (ixA < Win);
    const bool vxB = (ixB >= 0) && (ixB < Win);

    const bool mAA = vyA && vxA, mAB = vyA && vxB, mBA = vyB && vxA, mBB = vyB && vxB;
    const int oAA = iyA * Win + ixA, oAB = iyA * Win + ixB;
    const int oBA = iyB * Win + ixA, oBB = iyB * Win + ixB;
    const int wAA = kyA * 4 + kxA, wAB = kyA * 4 + kxB;
    const int wBA = kyB * 4 + kxA, wBB = kyB * 4 + kxB;

    float acc0 = bias[0];
    float acc1 = bias[1];
    const long hwin = (long)Hin * Win;
    const float* ip = in + (long)b * Cin * hwin;
    const float* wp = w;
    for (int ci = 0; ci < Cin; ++ci, ip += hwin, wp += 32) {
        float vAA = mAA ? ip[oAA] : 0.f;
        float vAB = mAB ? ip[oAB] : 0.f;
        float vBA = mBA ? ip[oBA] : 0.f;
        float vBB = mBB ? ip[oBB] : 0.f;
        acc0 += vAA * wp[wAA] + vAB * wp[wAB] + vBA * wp[wBA] + vBB * wp[wBB];
        acc1 += vAA * wp[16 + wAA] + vAB * wp[16 + wAB] + vBA * wp[16 + wBA] + vBB * wp[16 + wBB];
    }
    long o = (long)b * obs + y * W + x;
    out[o]      = acc0;
    out[o + HW] = acc1;
}

// ---------------------------------------------------------------------------
// Same transpose-conv, Cin split 8 ways within a 1024-thread block (Cin=661).
// ---------------------------------------------------------------------------
__global__ __launch_bounds__(1024) void upconv2_split_kernel(
    const float* __restrict__ in, int Cin, int Hin, int Win,
    const float* __restrict__ w, const float* __restrict__ bias,
    float* __restrict__ out, long obs)
{
    __shared__ float red[8][128][2];

    const int x = threadIdx.x & 127;
    const int s = threadIdx.x >> 7;       // split 0..7 (wave-uniform)
    const int y = blockIdx.x;
    const int b = blockIdx.y;

    const int p = (y + 1) & 1;
    const int kyA = p, kyB = p + 2;
    const int iyA = (y + 1 - kyA) >> 1;
    const int iyB = (y + 1 - kyB) >> 1;
    const bool vyA = (iyA >= 0) && (iyA < Hin);
    const bool vyB = (iyB >= 0) && (iyB < Hin);

    const int q = (x + 1) & 1;
    const int kxA = q, kxB = q + 2;
    const int ixA = (x + 1 - kxA) >> 1;
    const int ixB = (x + 1 - kxB) >> 1;
    const bool vxA = (ixA >= 0) && (ixA < Win);
    const bool vxB = (ixB >= 0) && (ixB < Win);

    const bool mAA = vyA && vxA, mAB = vyA && vxB, mBA = vyB && vxA, mBB = vyB && vxB;
    const int oAA = iyA * Win + ixA, oAB = iyA * Win + ixB;
    const int oBA = iyB * Win + ixA, oBB = iyB * Win + ixB;
    const int wAA = kyA * 4 + kxA, wAB = kyA * 4 + kxB;
    const int wBA = kyB * 4 + kxA, wBB = kyB * 4 + kxB;

    const int per = (Cin + 7) / 8;
    const int lo = s * per;
    const int hi = min(lo + per, Cin);

    float acc0 = 0.f, acc1 = 0.f;
    const long hwin = (long)Hin * Win;
    const float* ip = in + (long)b * Cin * hwin + (long)lo * hwin;
    const float* wp = w + lo * 32;
    for (int ci = lo; ci < hi; ++ci, ip += hwin, wp += 32) {
        float vAA = mAA ? ip[oAA] : 0.f;
        float vAB = mAB ? ip[oAB] : 0.f;
        float vBA = mBA ? ip[oBA] : 0.f;
        float vBB = mBB ? ip[oBB] : 0.f;
        acc0 += vAA * wp[wAA] + vAB * wp[wAB] + vBA * wp[wBA] + vBB * wp[wBB];
        acc1 += vAA * wp[16 + wAA] + vAB * wp[16 + wAB] + vBA * wp[16 + wBA] + vBB * wp[16 + wBB];
    }
    red[s][x][0] = acc0;
    red[s][x][1] = acc1;
    __syncthreads();
    if (s == 0) {
        float a0 = bias[0], a1 = bias[1];
        #pragma unroll
        for (int t = 0; t < 8; ++t) { a0 += red[t][x][0]; a1 += red[t][x][1]; }
        long o = (long)b * obs + y * W + x;
        out[o]      = a0;
        out[o + HW] = a1;
    }
}

// ---------------------------------------------------------------------------
// Bilinear warp (zeros padding) -> warped_n NHWC bf16 (pitch 96).
// ---------------------------------------------------------------------------
__global__ __launch_bounds__(512) void warp_nhwc_kernel(
    const float* __restrict__ tenTwo, const float* __restrict__ flow4,
    unsigned short* __restrict__ warped_n)
{
    __shared__ unsigned short tile[128 * 98];   // pitch 98 shorts: conflict-free b16 stores

    const int x   = threadIdx.x & 127;
    const int sub = threadIdx.x >> 7;           // 0..3, 24 channels each
    const int row = blockIdx.x;                 // b*H + y
    const int b = row >> 6;
    const int y = row & 63;

    const long fb = (long)b * 2 * HW + y * W + x;
    const float px = (float)x + 1.25f * flow4[fb];
    const float py = (float)y + 1.25f * flow4[fb + HW];

    const float x0f = floorf(px), y0f = floorf(py);
    const float wx = px - x0f, wy = py - y0f;
    const int x0 = (int)x0f, y0 = (int)y0f;
    const int x1 = x0 + 1,   y1 = y0 + 1;

    const bool vx0 = (x0 >= 0) && (x0 < W), vx1 = (x1 >= 0) && (x1 < W);
    const bool vy0 = (y0 >= 0) && (y0 < H), vy1 = (y1 >= 0) && (y1 < H);
    const int cx0 = min(max(x0, 0), W - 1), cx1 = min(max(x1, 0), W - 1);
    const int cy0 = min(max(y0, 0), H - 1), cy1 = min(max(y1, 0), H - 1);

    const float w00 = (1.f - wy) * (1.f - wx) * ((vy0 && vx0) ? 1.f : 0.f);
    const float w01 = (1.f - wy) * wx         * ((vy0 && vx1) ? 1.f : 0.f);
    const float w10 = wy * (1.f - wx)         * ((vy1 && vx0) ? 1.f : 0.f);
    const float w11 = wy * wx                 * ((vy1 && vx1) ? 1.f : 0.f);

    const int o00 = cy0 * W + cx0, o01 = cy0 * W + cx1;
    const int o10 = cy1 * W + cx0, o11 = cy1 * W + cx1;

    for (int i = 0; i < 24; ++i) {
        const int c = sub * 24 + i;
        const float* pch = tenTwo + (long)(b * 96 + c) * HW;
        const float v = pch[o00] * w00 + pch[o01] * w01 + pch[o10] * w10 + pch[o11] * w11;
        tile[x * 98 + c] = f2bf(v);
    }
    __syncthreads();

    // write out 128 px x 96 ch = 1536 uint4
    unsigned short* op = warped_n + (long)row * 128 * 96;
    for (int u = threadIdx.x; u < 1536; u += 512) {
        const int pxi = u / 12;
        const int cc = u - pxi * 12;
        const unsigned short* tp = tile + pxi * 98 + cc * 8;
        uint4 v;
        v.x = *(const unsigned*)(tp + 0);
        v.y = *(const unsigned*)(tp + 2);
        v.z = *(const unsigned*)(tp + 4);
        v.w = *(const unsigned*)(tp + 6);
        *(uint4*)(op + u * 8) = v;
    }
}

// ---------------------------------------------------------------------------
// Cost volume from NHWC bf16 warped + NCHW fp32 tenOne (held in 96 VGPRs).
// Writes bf16 into featn channels 448..528 (with leaky), chunked layout.
// ---------------------------------------------------------------------------
__global__ __launch_bounds__(512) void corr_kernel(
    const float* __restrict__ tenOne, const unsigned short* __restrict__ warped_n,
    unsigned short* __restrict__ featn)
{
    const int x  = threadIdx.x & 127;
    const int kg = threadIdx.x >> 7;     // 0..3
    const int row = blockIdx.x;          // b*H + y
    const int b = row >> 6;
    const int y = row & 63;
    const long pix = (long)row * W + x;

    float one[96];
    const float* op = tenOne + (long)b * 96 * HW + y * W + x;
    #pragma unroll
    for (int j = 0; j < 96; ++j) one[j] = op[(long)j * HW];

    const int k0 = kg * 21;
    const int k1 = min(k0 + 21, 81);
    for (int k = k0; k < k1; ++k) {
        const int dy = k / 9 - 4, dx = k % 9 - 4;   // wave-uniform
        const int yy = y + dy, xx = x + dx;
        float acc = 0.f;
        if (yy >= 0 && yy < H && xx >= 0 && xx < W) {
            const unsigned short* wp = warped_n + ((long)(b * H + yy) * W + xx) * 96;
            #pragma unroll
            for (int c4 = 0; c4 < 12; ++c4) {
                const uint4 v = *(const uint4*)(wp + c4 * 8);
                unsigned uu[4] = {v.x, v.y, v.z, v.w};
                #pragma unroll
                for (int e = 0; e < 4; ++e) {
                    const float flo = __uint_as_float(uu[e] << 16);
                    const float fhi = __uint_as_float(uu[e] & 0xffff0000u);
                    acc += one[c4 * 8 + e * 2] * flo + one[c4 * 8 + e * 2 + 1] * fhi;
                }
            }
        }
        const int c = 448 + k;
        featn[((long)(c >> 5) * NPIX + pix) * 32 + (c & 31)] = f2bf(leakyf(acc * (1.f / 96.f)));
    }
}

// ---------------------------------------------------------------------------
// Pack tenOne/flow/upfeat (fp32) into featn bf16 channels 528..639.
// (528 is a placeholder overwritten later by corr; 629..639 are zero pad.)
// ---------------------------------------------------------------------------
__global__ void pack_kernel(const float* __restrict__ one, const float* __restrict__ flow4,
                            const float* __restrict__ up4, unsigned short* __restrict__ featn)
{
    const long t = (long)blockIdx.x * 256 + threadIdx.x;    // pixel 0..65535
    const long b = t >> 13;
    const long p = t & (HW - 1);
    unsigned short buf[8];
    for (int cc = 0; cc < 14; ++cc) {
        const int cbase = 528 + cc * 8;
        #pragma unroll
        for (int j = 0; j < 8; ++j) {
            const int c = cbase + j;
            float v;
            if (c < 529)      v = 0.f;
            else if (c < 625) v = one[(b * 96 + (c - 529)) * HW + p];
            else if (c < 627) v = flow4[(b * 2 + (c - 625)) * HW + p];
            else if (c < 629) v = up4[(b * 2 + (c - 627)) * HW + p];
            else              v = 0.f;
            buf[j] = f2bf(v);
        }
        *(uint4*)(featn + ((long)(cbase >> 5) * NPIX + t) * 32 + (cbase & 31)) = *(const uint4*)buf;
    }
}

// ---------------------------------------------------------------------------
// feat_nhwc (chunked) bf16 -> d_out feat region fp32 NCHW (B,629,H,W)
// ---------------------------------------------------------------------------
__global__ void unpack_kernel(const unsigned short* __restrict__ featn, float* __restrict__ out)
{
    const long t = (long)blockIdx.x * 256 + threadIdx.x;    // pixel
    const long b = t >> 13;
    const long p = t & (HW - 1);
    const unsigned short* f = featn + t * 32;
    float* ob = out + b * 629L * HW + p;
    for (int cc = 0; cc < 20; ++cc) {
        const unsigned short* fc = f + (long)cc * CHSZ;
        #pragma unroll
        for (int g = 0; g < 4; ++g) {
            uint4 v = *(const uint4*)(fc + g * 8);
            unsigned short s[8];
            *(uint4*)s = v;
            #pragma unroll
            for (int j = 0; j < 8; ++j) {
                const int c = cc * 32 + g * 8 + j;
                if (c < 629) ob[(long)c * HW] = bf2f(s[j]);
            }
        }
    }
}

// ---------------------------------------------------------------------------
// Weight convert: fp32 OIHW -> bf16 fragment-ordered [kc][tap][nf][lane][8],
// so a wave's B-fragment load is 1KB fully contiguous.
// lane = q*16 + l15 holds co = nf*16+l15, ci = kc*32 + q*8 + j.
// ---------------------------------------------------------------------------
__global__ void wcvt_kernel(const float* __restrict__ w, unsigned short* __restrict__ wt,
                            int Cout, int Cin, int NFC, long total)
{
    const long t = (long)blockIdx.x * 256 + threadIdx.x;
    if (t >= total) return;
    const int j    = (int)(t & 7);
    const int lane = (int)((t >> 3) & 63);
    long r = t >> 9;
    const int nf  = (int)(r % NFC);  r /= NFC;
    const int tap = (int)(r % 9);
    const int kc  = (int)(r / 9);
    const int l15 = lane & 15, q = lane >> 4;
    const int co = nf * 16 + l15;
    const int ci = kc * 32 + q * 8 + j;
    float v = 0.f;
    if (co < Cout && ci < Cin) v = w[((long)co * Cin + ci) * 9 + tap];
    wt[t] = f2bf(v);
}

// ---------------------------------------------------------------------------
// Implicit-GEMM 3x3 conv, bf16 MFMA 16x16x32, fp32 accum.
// R2: chunked-channel featn -> stage loads are contiguous 1KB/wave-inst;
//     fragment-ordered weights -> B loads are contiguous 1KB/wave-inst.
//     Full 128-px rows (512 blocks), 4 waves, 2 M-tiles/wave; reg-prefetch
//     of next K-chunk overlaps global latency with MFMA.
// ---------------------------------------------------------------------------
template<int NF>
__global__ __launch_bounds__(256) void conv_mfma(
    const unsigned short* __restrict__ featn, int c0, int nchunks,
    const unsigned short* __restrict__ wt, const float* __restrict__ bias,
    unsigned short* __restrict__ outf, int oc0, float* __restrict__ flowout)
{
    __shared__ unsigned short tile[3 * 130 * 40];   // [r*130+xx][32ch + pad 8]

    const int row = blockIdx.x;          // b*H + y
    const int b = row >> 6;
    const int y = row & 63;
    const int tid = threadIdx.x;
    const int lane = tid & 63;
    const int wv = tid >> 6;
    const int l15 = lane & 15;
    const int q = lane >> 4;

    // staging descriptors: 1560 uint4 units (3 rows x 130 px x 4 subs of 16B)
    int gofs[7];
    int lofs[7];
    #pragma unroll
    for (int it = 0; it < 7; ++it) {
        const int u = tid + it * 256;
        const int pr = u >> 2;           // pixel unit 0..389
        const int sub = u & 3;
        const int r = (pr >= 260) ? 2 : (pr >= 130 ? 1 : 0);
        const int xx = pr - r * 130;
        const int gy = y + r - 1, gx = xx - 1;
        const bool inu = (u < 1560);
        const bool inb = inu && (gy >= 0) && (gy < H) && (gx >= 0) && (gx < W);
        gofs[it] = inb ? (((b * H + gy) * W + gx) * 32 + sub * 8) : -1;
        lofs[it] = inu ? (pr * 40 + sub * 8) : -1;
    }

    floatx4 acc[2][NF];
    #pragma unroll
    for (int mf = 0; mf < 2; ++mf)
        #pragma unroll
        for (int nf = 0; nf < NF; ++nf)
            acc[mf][nf] = (floatx4){0.f, 0.f, 0.f, 0.f};

    const unsigned short* fb = featn + (long)(c0 >> 5) * CHSZ;   // chunk base
    const unsigned short* wlane = wt + lane * 8;

    // prefetch chunk 0 into registers
    uint4 rg[7];
    #pragma unroll
    for (int it = 0; it < 7; ++it)
        rg[it] = (gofs[it] >= 0) ? *(const uint4*)(fb + gofs[it]) : make_uint4(0u, 0u, 0u, 0u);

    for (int kc = 0; kc < nchunks; ++kc) {
        if (kc) __syncthreads();
        #pragma unroll
        for (int it = 0; it < 7; ++it)
            if (lofs[it] >= 0) *(uint4*)&tile[lofs[it]] = rg[it];
        __syncthreads();

        // issue next chunk's loads before MFMA phase (latency hides under MFMA)
        if (kc + 1 < nchunks) {
            const unsigned short* fn = fb + (long)(kc + 1) * CHSZ;
            #pragma unroll
            for (int it = 0; it < 7; ++it)
                rg[it] = (gofs[it] >= 0) ? *(const uint4*)(fn + gofs[it]) : make_uint4(0u, 0u, 0u, 0u);
        }

        #pragma unroll
        for (int ky = 0; ky < 3; ++ky) {
            #pragma unroll
            for (int kx = 0; kx < 3; ++kx) {
                const int tap = ky * 3 + kx;
                const short8 a0 = *(const short8*)&tile[(ky * 130 + wv * 32 + l15 + kx) * 40 + q * 8];
                const short8 a1 = *(const short8*)&tile[(ky * 130 + wv * 32 + 16 + l15 + kx) * 40 + q * 8];
                const unsigned short* wb = wlane + ((long)(kc * 9 + tap) * NF << 9);
                #pragma unroll
                for (int nf = 0; nf < NF; ++nf) {
                    const short8 bf = *(const short8*)(wb + ((long)nf << 9));
                    acc[0][nf] = __builtin_amdgcn_mfma_f32_16x16x32_bf16(a0, bf, acc[0][nf], 0, 0, 0);
                    acc[1][nf] = __builtin_amdgcn_mfma_f32_16x16x32_bf16(a1, bf, acc[1][nf], 0, 0, 0);
                }
            }
        }
    }

    if (flowout == nullptr) {
        float bv[NF];
        #pragma unroll
        for (int nf = 0; nf < NF; ++nf) bv[nf] = bias[nf * 16 + l15];
        const int cchunk0 = oc0 >> 5;
        #pragma unroll
        for (int mf = 0; mf < 2; ++mf) {
            const int xb = wv * 32 + mf * 16 + q * 4;
            #pragma unroll
            for (int r = 0; r < 4; ++r) {
                const long pixo = (long)row * W + xb + r;
                #pragma unroll
                for (int nf = 0; nf < NF; ++nf) {
                    float v = acc[mf][nf][r] + bv[nf];
                    const long a = ((long)(cchunk0 + (nf >> 1)) * NPIX + pixo) * 32 + (nf & 1) * 16 + l15;
                    outf[a] = f2bf(leakyf(v));
                }
            }
        }
    } else {
        if (l15 < 2) {
            const float bb = bias[l15];
            #pragma unroll
            for (int mf = 0; mf < 2; ++mf) {
                const int xb = wv * 32 + mf * 16 + q * 4;
                #pragma unroll
                for (int r = 0; r < 4; ++r) {
                    float v = acc[mf][0][r] + bb;
                    flowout[((long)b * 2 + l15) * HW + y * W + xb + r] = leakyf(v);
                }
            }
        }
    }
}

// ---------------------------------------------------------------------------
extern "C" void kernel_launch(void* const* d_in, const int* in_sizes, int n_in,
                              void* d_out, int out_size, void* d_ws, size_t ws_size,
                              hipStream_t stream)
{
    const float* tenOne    = (const float*)d_in[0];
    const float* tenTwo    = (const float*)d_in[1];
    const float* prev_flow = (const float*)d_in[2];
    const float* prev_feat = (const float*)d_in[3];
    const float* w_upflow  = (const float*)d_in[4];
    const float* b_upflow  = (const float*)d_in[5];
    const float* w_upfeat  = (const float*)d_in[6];
    const float* b_upfeat  = (const float*)d_in[7];
    const float* wc[6] = {(const float*)d_in[8],  (const float*)d_in[10], (const float*)d_in[12],
                          (const float*)d_in[14], (const float*)d_in[16], (const float*)d_in[18]};
    const float* bc[6] = {(const float*)d_in[9],  (const float*)d_in[11], (const float*)d_in[13],
                          (const float*)d_in[15], (const float*)d_in[17], (const float*)d_in[19]};

    float* flow_out = (float*)d_out;                  // (B,2,H,W)
    float* feat_out = flow_out + (long)NB * 2 * HW;   // (B,629,H,W)

    // workspace layout (bytes)
    // featn: 20 chunks x 65536 px x 32 ch x 2B = 83,886,080
    // warped_n ALIASES featn chunks 0..2 (12,582,912 B): chunks 0..2 are only
    // written by conv4/conv5, which run after corr has consumed warped_n.
    char* ws = (char*)d_ws;
    unsigned short* featn    = (unsigned short*)ws;
    unsigned short* warped_n = (unsigned short*)ws;                 // alias, see above
    float* flow4 = (float*)(ws + 83886080L);                        // 524,288
    float* up4   = (float*)(ws + 84410368L);                        // 524,288
    unsigned short* wt1 = (unsigned short*)(ws + 84934656L);        // 442,368
    unsigned short* wt2 = (unsigned short*)(ws + 85377024L);        // 737,280
    unsigned short* wt3 = (unsigned short*)(ws + 86114304L);        // 774,144
    unsigned short* wt4 = (unsigned short*)(ws + 86888448L);        // 626,688
    unsigned short* wt5 = (unsigned short*)(ws + 87515136L);        // 350,208
    unsigned short* wt6 = (unsigned short*)(ws + 87865344L);        // 184,320
    unsigned short* wts[6] = {wt1, wt2, wt3, wt4, wt5, wt6};

    const int Cout[6] = {128, 128, 96, 64, 32, 2};
    const int Cin [6] = {181, 309, 437, 533, 597, 629};
    const int NCH [6] = {6, 10, 14, 17, 19, 20};      // K chunks (Kpad/32)
    const int NFC [6] = {8, 8, 6, 4, 2, 1};           // CoPd/16
    const int c0  [6] = {448, 320, 192, 96, 32, 0};
    const int oc0 [6] = {320, 192, 96, 32, 0, 0};

    for (int i = 0; i < 6; ++i) {
        long total = (long)NCH[i] * 9 * NFC[i] * 512;
        wcvt_kernel<<<(int)((total + 255) / 256), 256, 0, stream>>>(
            wc[i], wts[i], Cout[i], Cin[i], NFC[i], total);
    }

    // upsample flow (small) + feat (split-reduce)
    upconv2_kernel<<<dim3(H, NB), W, 0, stream>>>(prev_flow, 2, 32, 64,
                                                  w_upflow, b_upflow, flow4, (long)(2 * HW));
    upconv2_split_kernel<<<dim3(H, NB), 1024, 0, stream>>>(prev_feat, 661, 32, 64,
                                                           w_upfeat, b_upfeat, up4, (long)(2 * HW));

    // pack static channels, warp, correlation
    pack_kernel<<<256, 256, 0, stream>>>(tenOne, flow4, up4, featn);
    warp_nhwc_kernel<<<512, 512, 0, stream>>>(tenTwo, flow4, warped_n);
    corr_kernel<<<512, 512, 0, stream>>>(tenOne, warped_n, featn);

    // conv chain (MFMA)
    conv_mfma<8><<<512, 256, 0, stream>>>(featn, c0[0], NCH[0], wts[0], bc[0], featn, oc0[0], nullptr);
    conv_mfma<8><<<512, 256, 0, stream>>>(featn, c0[1], NCH[1], wts[1], bc[1], featn, oc0[1], nullptr);
    conv_mfma<6><<<512, 256, 0, stream>>>(featn, c0[2], NCH[2], wts[2], bc[2], featn, oc0[2], nullptr);
    conv_mfma<4><<<512, 256, 0, stream>>>(featn, c0[3], NCH[3], wts[3], bc[3], featn, oc0[3], nullptr);
    conv_mfma<2><<<512, 256, 0, stream>>>(featn, c0[4], NCH[4], wts[4], bc[4], featn, oc0[4], nullptr);
    conv_mfma<1><<<512, 256, 0, stream>>>(featn, c0[5], NCH[5], wts[5], bc[5], featn, 0, flow_out);

    // unpack feat to fp32 NCHW output
    unpack_kernel<<<256, 256, 0, stream>>>(featn, feat_out);
}

// Round 3
// 901.594 us; speedup vs baseline: 2.1477x; 1.2956x over previous
//
#include <hip/hip_runtime.h>

#define W 128
#define H 64
#define HW 8192
#define NB 8
#define NPIX 65536              // NB*HW
#define CHSZ 2097152L           // shorts per channel-chunk: NPIX*32

typedef __attribute__((ext_vector_type(8))) short short8;
typedef __attribute__((ext_vector_type(4))) float floatx4;

__device__ __forceinline__ float leakyf(float v) { return v >= 0.f ? v : 0.1f * v; }

__device__ __forceinline__ unsigned short f2bf(float f) {
    unsigned u = __float_as_uint(f);
    u += 0x7FFF + ((u >> 16) & 1);          // RNE
    return (unsigned short)(u >> 16);
}
__device__ __forceinline__ float bf2f(unsigned short s) {
    return __uint_as_float((unsigned)s << 16);
}

// featn layout: chunked-channel NHWC. addr(c, pix) = ((c>>5)*NPIX + pix)*32 + (c&31)
// chunks 0..19 cover channels 0..639 (629 real + zero pad).

// ---------------------------------------------------------------------------
// ConvTranspose2d k=4 s=2 p=1, Cout=2, small Cin (used for prev_flow, Cin=2)
// ---------------------------------------------------------------------------
__global__ void upconv2_kernel(const float* __restrict__ in, int Cin, int Hin, int Win,
                               const float* __restrict__ w, const float* __restrict__ bias,
                               float* __restrict__ out, long obs)
{
    const int x = threadIdx.x;
    const int y = blockIdx.x;
    const int b = blockIdx.y;

    const int p = (y + 1) & 1;
    const int kyA = p, kyB = p + 2;
    const int iyA = (y + 1 - kyA) >> 1;
    const int iyB = (y + 1 - kyB) >> 1;
    const bool vyA = (iyA >= 0) && (iyA < Hin);
    const bool vyB = (iyB >= 0) && (iyB < Hin);

    const int q = (x + 1) & 1;
    const int kxA = q, kxB = q + 2;
    const int ixA = (x + 1 - kxA) >> 1;
    const int ixB = (x + 1 - kxB) >> 1;
    const bool vxA = (ixA >= 0) && (ixA < Win);
    const bool vxB = (ixB >= 0) && (ixB < Win);

    const bool mAA = vyA && vxA, mAB = vyA && vxB, mBA = vyB && vxA, mBB = vyB && vxB;
    const int oAA = iyA * Win + ixA, oAB = iyA * Win + ixB;
    const int oBA = iyB * Win + ixA, oBB = iyB * Win + ixB;
    const int wAA = kyA * 4 + kxA, wAB = kyA * 4 + kxB;
    const int wBA = kyB * 4 + kxA, wBB = kyB * 4 + kxB;

    float acc0 = bias[0];
    float acc1 = bias[1];
    const long hwin = (long)Hin * Win;
    const float* ip = in + (long)b * Cin * hwin;
    const float* wp = w;
    for (int ci = 0; ci < Cin; ++ci, ip += hwin, wp += 32) {
        float vAA = mAA ? ip[oAA] : 0.f;
        float vAB = mAB ? ip[oAB] : 0.f;
        float vBA = mBA ? ip[oBA] : 0.f;
        float vBB = mBB ? ip[oBB] : 0.f;
        acc0 += vAA * wp[wAA] + vAB * wp[wAB] + vBA * wp[wBA] + vBB * wp[wBB];
        acc1 += vAA * wp[16 + wAA] + vAB * wp[16 + wAB] + vBA * wp[16 + wBA] + vBB * wp[16 + wBB];
    }
    long o = (long)b * obs + y * W + x;
    out[o]      = acc0;
    out[o + HW] = acc1;
}

// ---------------------------------------------------------------------------
// Same transpose-conv, Cin split 8 ways within a 1024-thread block (Cin=661).
// ---------------------------------------------------------------------------
__global__ __launch_bounds__(1024) void upconv2_split_kernel(
    const float* __restrict__ in, int Cin, int Hin, int Win,
    const float* __restrict__ w, const float* __restrict__ bias,
    float* __restrict__ out, long obs)
{
    __shared__ float red[8][128][2];

    const int x = threadIdx.x & 127;
    const int s = threadIdx.x >> 7;       // split 0..7 (wave-uniform)
    const int y = blockIdx.x;
    const int b = blockIdx.y;

    const int p = (y + 1) & 1;
    const int kyA = p, kyB = p + 2;
    const int iyA = (y + 1 - kyA) >> 1;
    const int iyB = (y + 1 - kyB) >> 1;
    const bool vyA = (iyA >= 0) && (iyA < Hin);
    const bool vyB = (iyB >= 0) && (iyB < Hin);

    const int q = (x + 1) & 1;
    const int kxA = q, kxB = q + 2;
    const int ixA = (x + 1 - kxA) >> 1;
    const int ixB = (x + 1 - kxB) >> 1;
    const bool vxA = (ixA >= 0) && (ixA < Win);
    const bool vxB = (ixB >= 0) && (ixB < Win);

    const bool mAA = vyA && vxA, mAB = vyA && vxB, mBA = vyB && vxA, mBB = vyB && vxB;
    const int oAA = iyA * Win + ixA, oAB = iyA * Win + ixB;
    const int oBA = iyB * Win + ixA, oBB = iyB * Win + ixB;
    const int wAA = kyA * 4 + kxA, wAB = kyA * 4 + kxB;
    const int wBA = kyB * 4 + kxA, wBB = kyB * 4 + kxB;

    const int per = (Cin + 7) / 8;
    const int lo = s * per;
    const int hi = min(lo + per, Cin);

    float acc0 = 0.f, acc1 = 0.f;
    const long hwin = (long)Hin * Win;
    const float* ip = in + (long)b * Cin * hwin + (long)lo * hwin;
    const float* wp = w + lo * 32;
    for (int ci = lo; ci < hi; ++ci, ip += hwin, wp += 32) {
        float vAA = mAA ? ip[oAA] : 0.f;
        float vAB = mAB ? ip[oAB] : 0.f;
        float vBA = mBA ? ip[oBA] : 0.f;
        float vBB = mBB ? ip[oBB] : 0.f;
        acc0 += vAA * wp[wAA] + vAB * wp[wAB] + vBA * wp[wBA] + vBB * wp[wBB];
        acc1 += vAA * wp[16 + wAA] + vAB * wp[16 + wAB] + vBA * wp[16 + wBA] + vBB * wp[16 + wBB];
    }
    red[s][x][0] = acc0;
    red[s][x][1] = acc1;
    __syncthreads();
    if (s == 0) {
        float a0 = bias[0], a1 = bias[1];
        #pragma unroll
        for (int t = 0; t < 8; ++t) { a0 += red[t][x][0]; a1 += red[t][x][1]; }
        long o = (long)b * obs + y * W + x;
        out[o]      = a0;
        out[o + HW] = a1;
    }
}

// ---------------------------------------------------------------------------
// Bilinear warp (zeros padding) -> warped_n NHWC bf16 (pitch 96).
// ---------------------------------------------------------------------------
__global__ __launch_bounds__(512) void warp_nhwc_kernel(
    const float* __restrict__ tenTwo, const float* __restrict__ flow4,
    unsigned short* __restrict__ warped_n)
{
    __shared__ unsigned short tile[128 * 98];   // pitch 98 shorts: conflict-free b16 stores

    const int x   = threadIdx.x & 127;
    const int sub = threadIdx.x >> 7;           // 0..3, 24 channels each
    const int row = blockIdx.x;                 // b*H + y
    const int b = row >> 6;
    const int y = row & 63;

    const long fb = (long)b * 2 * HW + y * W + x;
    const float px = (float)x + 1.25f * flow4[fb];
    const float py = (float)y + 1.25f * flow4[fb + HW];

    const float x0f = floorf(px), y0f = floorf(py);
    const float wx = px - x0f, wy = py - y0f;
    const int x0 = (int)x0f, y0 = (int)y0f;
    const int x1 = x0 + 1,   y1 = y0 + 1;

    const bool vx0 = (x0 >= 0) && (x0 < W), vx1 = (x1 >= 0) && (x1 < W);
    const bool vy0 = (y0 >= 0) && (y0 < H), vy1 = (y1 >= 0) && (y1 < H);
    const int cx0 = min(max(x0, 0), W - 1), cx1 = min(max(x1, 0), W - 1);
    const int cy0 = min(max(y0, 0), H - 1), cy1 = min(max(y1, 0), H - 1);

    const float w00 = (1.f - wy) * (1.f - wx) * ((vy0 && vx0) ? 1.f : 0.f);
    const float w01 = (1.f - wy) * wx         * ((vy0 && vx1) ? 1.f : 0.f);
    const float w10 = wy * (1.f - wx)         * ((vy1 && vx0) ? 1.f : 0.f);
    const float w11 = wy * wx                 * ((vy1 && vx1) ? 1.f : 0.f);

    const int o00 = cy0 * W + cx0, o01 = cy0 * W + cx1;
    const int o10 = cy1 * W + cx0, o11 = cy1 * W + cx1;

    for (int i = 0; i < 24; ++i) {
        const int c = sub * 24 + i;
        const float* pch = tenTwo + (long)(b * 96 + c) * HW;
        const float v = pch[o00] * w00 + pch[o01] * w01 + pch[o10] * w10 + pch[o11] * w11;
        tile[x * 98 + c] = f2bf(v);
    }
    __syncthreads();

    // write out 128 px x 96 ch = 1536 uint4
    unsigned short* op = warped_n + (long)row * 128 * 96;
    for (int u = threadIdx.x; u < 1536; u += 512) {
        const int pxi = u / 12;
        const int cc = u - pxi * 12;
        const unsigned short* tp = tile + pxi * 98 + cc * 8;
        uint4 v;
        v.x = *(const unsigned*)(tp + 0);
        v.y = *(const unsigned*)(tp + 2);
        v.z = *(const unsigned*)(tp + 4);
        v.w = *(const unsigned*)(tp + 6);
        *(uint4*)(op + u * 8) = v;
    }
}

// ---------------------------------------------------------------------------
// Cost volume from NHWC bf16 warped + NCHW fp32 tenOne (held in 96 VGPRs).
// Writes bf16 into featn channels 448..528 (with leaky), chunked layout.
// ---------------------------------------------------------------------------
__global__ __launch_bounds__(512) void corr_kernel(
    const float* __restrict__ tenOne, const unsigned short* __restrict__ warped_n,
    unsigned short* __restrict__ featn)
{
    const int x  = threadIdx.x & 127;
    const int kg = threadIdx.x >> 7;     // 0..3
    const int row = blockIdx.x;          // b*H + y
    const int b = row >> 6;
    const int y = row & 63;
    const long pix = (long)row * W + x;

    float one[96];
    const float* op = tenOne + (long)b * 96 * HW + y * W + x;
    #pragma unroll
    for (int j = 0; j < 96; ++j) one[j] = op[(long)j * HW];

    const int k0 = kg * 21;
    const int k1 = min(k0 + 21, 81);
    for (int k = k0; k < k1; ++k) {
        const int dy = k / 9 - 4, dx = k % 9 - 4;   // wave-uniform
        const int yy = y + dy, xx = x + dx;
        float acc = 0.f;
        if (yy >= 0 && yy < H && xx >= 0 && xx < W) {
            const unsigned short* wp = warped_n + ((long)(b * H + yy) * W + xx) * 96;
            #pragma unroll
            for (int c4 = 0; c4 < 12; ++c4) {
                const uint4 v = *(const uint4*)(wp + c4 * 8);
                unsigned uu[4] = {v.x, v.y, v.z, v.w};
                #pragma unroll
                for (int e = 0; e < 4; ++e) {
                    const float flo = __uint_as_float(uu[e] << 16);
                    const float fhi = __uint_as_float(uu[e] & 0xffff0000u);
                    acc += one[c4 * 8 + e * 2] * flo + one[c4 * 8 + e * 2 + 1] * fhi;
                }
            }
        }
        const int c = 448 + k;
        featn[((long)(c >> 5) * NPIX + pix) * 32 + (c & 31)] = f2bf(leakyf(acc * (1.f / 96.f)));
    }
}

// ---------------------------------------------------------------------------
// Pack tenOne/flow/upfeat (fp32) into featn bf16 channels 528..639.
// (528 is a placeholder overwritten later by corr; 629..639 are zero pad.)
// ---------------------------------------------------------------------------
__global__ void pack_kernel(const float* __restrict__ one, const float* __restrict__ flow4,
                            const float* __restrict__ up4, unsigned short* __restrict__ featn)
{
    const long t = (long)blockIdx.x * 256 + threadIdx.x;    // pixel 0..65535
    const long b = t >> 13;
    const long p = t & (HW - 1);
    unsigned short buf[8];
    for (int cc = 0; cc < 14; ++cc) {
        const int cbase = 528 + cc * 8;
        #pragma unroll
        for (int j = 0; j < 8; ++j) {
            const int c = cbase + j;
            float v;
            if (c < 529)      v = 0.f;
            else if (c < 625) v = one[(b * 96 + (c - 529)) * HW + p];
            else if (c < 627) v = flow4[(b * 2 + (c - 625)) * HW + p];
            else if (c < 629) v = up4[(b * 2 + (c - 627)) * HW + p];
            else              v = 0.f;
            buf[j] = f2bf(v);
        }
        *(uint4*)(featn + ((long)(cbase >> 5) * NPIX + t) * 32 + (cbase & 31)) = *(const uint4*)buf;
    }
}

// ---------------------------------------------------------------------------
// feat_nhwc (chunked) bf16 -> d_out feat region fp32 NCHW (B,629,H,W)
// ---------------------------------------------------------------------------
__global__ void unpack_kernel(const unsigned short* __restrict__ featn, float* __restrict__ out)
{
    const long t = (long)blockIdx.x * 256 + threadIdx.x;    // pixel
    const long b = t >> 13;
    const long p = t & (HW - 1);
    const unsigned short* f = featn + t * 32;
    float* ob = out + b * 629L * HW + p;
    for (int cc = 0; cc < 20; ++cc) {
        const unsigned short* fc = f + (long)cc * CHSZ;
        #pragma unroll
        for (int g = 0; g < 4; ++g) {
            uint4 v = *(const uint4*)(fc + g * 8);
            unsigned short s[8];
            *(uint4*)s = v;
            #pragma unroll
            for (int j = 0; j < 8; ++j) {
                const int c = cc * 32 + g * 8 + j;
                if (c < 629) ob[(long)c * HW] = bf2f(s[j]);
            }
        }
    }
}

// ---------------------------------------------------------------------------
// Weight convert: fp32 OIHW -> bf16 fragment-ordered [kc][tap][nf][lane][8],
// so a wave's B-fragment load is 1KB fully contiguous.
// lane = q*16 + l15 holds co = nf*16+l15, ci = kc*32 + q*8 + j.
// ---------------------------------------------------------------------------
__global__ void wcvt_kernel(const float* __restrict__ w, unsigned short* __restrict__ wt,
                            int Cout, int Cin, int NFC, long total)
{
    const long t = (long)blockIdx.x * 256 + threadIdx.x;
    if (t >= total) return;
    const int j    = (int)(t & 7);
    const int lane = (int)((t >> 3) & 63);
    long r = t >> 9;
    const int nf  = (int)(r % NFC);  r /= NFC;
    const int tap = (int)(r % 9);
    const int kc  = (int)(r / 9);
    const int l15 = lane & 15, q = lane >> 4;
    const int co = nf * 16 + l15;
    const int ci = kc * 32 + q * 8 + j;
    float v = 0.f;
    if (co < Cout && ci < Cin) v = w[((long)co * Cin + ci) * 9 + tap];
    wt[t] = f2bf(v);
}

// ---------------------------------------------------------------------------
// Implicit-GEMM 3x3 conv, bf16 MFMA 16x16x32, fp32 accum.
// R3: 8-wave blocks (512 thr): wave = (mg = M-tile 32px, nh = N-half).
//     NF split across wave pairs -> same weight traffic as 4-wave, 2x TLP
//     (4 waves/SIMD). LDS double-buffered -> ONE barrier per K-chunk; rg
//     prefetch depth = full chunk (loads for kc+2 issued in iter kc).
// ---------------------------------------------------------------------------
template<int NFT>
__global__ __launch_bounds__(512, 4) void conv_mfma(
    const unsigned short* __restrict__ featn, int c0, int nchunks,
    const unsigned short* __restrict__ wt, const float* __restrict__ bias,
    unsigned short* __restrict__ outf, int oc0, float* __restrict__ flowout)
{
    constexpr int NFW = (NFT + 1) / 2;          // frags per wave (N-split 2)
    __shared__ unsigned short tile[2][3 * 130 * 40];   // 62,400 B

    const int row = blockIdx.x;          // b*H + y
    const int b = row >> 6;
    const int y = row & 63;
    const int tid = threadIdx.x;
    const int lane = tid & 63;
    const int wave = tid >> 6;
    const int mg = wave & 3;             // 32-px M-tile group
    const int nh = wave >> 2;            // N half (0/1)
    const int l15 = lane & 15;
    const int q = lane >> 4;
    const bool active = (nh * NFW) < NFT;   // NFT=1: nh=1 waves stage only

    // staging descriptors: 1560 uint4 units (3 rows x 130 px x 4 subs of 16B)
    int gofs[4];
    int lofs[4];
    #pragma unroll
    for (int it = 0; it < 4; ++it) {
        const int u = tid + it * 512;
        const int pr = u >> 2;           // pixel unit 0..389
        const int sub = u & 3;
        const int r = (pr >= 260) ? 2 : (pr >= 130 ? 1 : 0);
        const int xx = pr - r * 130;
        const int gy = y + r - 1, gx = xx - 1;
        const bool inu = (u < 1560);
        const bool inb = inu && (gy >= 0) && (gy < H) && (gx >= 0) && (gx < W);
        gofs[it] = inb ? (((b * H + gy) * W + gx) * 32 + sub * 8) : -1;
        lofs[it] = inu ? (pr * 40 + sub * 8) : -1;
    }

    floatx4 acc[2][NFW];
    #pragma unroll
    for (int mf = 0; mf < 2; ++mf)
        #pragma unroll
        for (int nf = 0; nf < NFW; ++nf)
            acc[mf][nf] = (floatx4){0.f, 0.f, 0.f, 0.f};

    const unsigned short* fb = featn + (long)(c0 >> 5) * CHSZ;   // chunk base
    const unsigned short* wlane = wt + lane * 8;

    // prologue: load chunk 0, stage into buf 0, issue chunk 1 loads
    uint4 rg[4];
    #pragma unroll
    for (int it = 0; it < 4; ++it)
        rg[it] = (gofs[it] >= 0) ? *(const uint4*)(fb + gofs[it]) : make_uint4(0u, 0u, 0u, 0u);
    #pragma unroll
    for (int it = 0; it < 4; ++it)
        if (lofs[it] >= 0) *(uint4*)&tile[0][lofs[it]] = rg[it];
    if (nchunks > 1) {
        const unsigned short* fn = fb + CHSZ;
        #pragma unroll
        for (int it = 0; it < 4; ++it)
            rg[it] = (gofs[it] >= 0) ? *(const uint4*)(fn + gofs[it]) : make_uint4(0u, 0u, 0u, 0u);
    }
    __syncthreads();

    for (int kc = 0; kc < nchunks; ++kc) {
        const int cur = kc & 1;

        // stage chunk kc+1 into the other buffer (readers finished at the
        // barrier ending iter kc-1), then issue chunk kc+2 loads.
        if (kc + 1 < nchunks) {
            #pragma unroll
            for (int it = 0; it < 4; ++it)
                if (lofs[it] >= 0) *(uint4*)&tile[cur ^ 1][lofs[it]] = rg[it];
        }
        if (kc + 2 < nchunks) {
            const unsigned short* fn = fb + (long)(kc + 2) * CHSZ;
            #pragma unroll
            for (int it = 0; it < 4; ++it)
                rg[it] = (gofs[it] >= 0) ? *(const uint4*)(fn + gofs[it]) : make_uint4(0u, 0u, 0u, 0u);
        }

        if (active) {
            #pragma unroll
            for (int ky = 0; ky < 3; ++ky) {
                #pragma unroll
                for (int kx = 0; kx < 3; ++kx) {
                    const int tap = ky * 3 + kx;
                    const short8 a0 = *(const short8*)&tile[cur][(ky * 130 + mg * 32 + l15 + kx) * 40 + q * 8];
                    const short8 a1 = *(const short8*)&tile[cur][(ky * 130 + mg * 32 + 16 + l15 + kx) * 40 + q * 8];
                    const unsigned short* wb = wlane + ((long)((kc * 9 + tap) * NFT + nh * NFW) << 9);
                    #pragma unroll
                    for (int nf = 0; nf < NFW; ++nf) {
                        const short8 bf = *(const short8*)(wb + ((long)nf << 9));
                        acc[0][nf] = __builtin_amdgcn_mfma_f32_16x16x32_bf16(a0, bf, acc[0][nf], 0, 0, 0);
                        acc[1][nf] = __builtin_amdgcn_mfma_f32_16x16x32_bf16(a1, bf, acc[1][nf], 0, 0, 0);
                    }
                }
            }
        }
        __syncthreads();
    }

    if (flowout == nullptr) {
        if (active) {
            float bv[NFW];
            #pragma unroll
            for (int nf = 0; nf < NFW; ++nf) bv[nf] = bias[(nh * NFW + nf) * 16 + l15];
            const int cchunk0 = oc0 >> 5;
            #pragma unroll
            for (int mf = 0; mf < 2; ++mf) {
                const int xb = mg * 32 + mf * 16 + q * 4;
                #pragma unroll
                for (int r = 0; r < 4; ++r) {
                    const long pixo = (long)row * W + xb + r;
                    #pragma unroll
                    for (int nf = 0; nf < NFW; ++nf) {
                        const int nfg = nh * NFW + nf;
                        float v = acc[mf][nf][r] + bv[nf];
                        const long a = ((long)(cchunk0 + (nfg >> 1)) * NPIX + pixo) * 32 + (nfg & 1) * 16 + l15;
                        outf[a] = f2bf(leakyf(v));
                    }
                }
            }
        }
    } else {
        if (active && l15 < 2) {
            const float bb = bias[l15];
            #pragma unroll
            for (int mf = 0; mf < 2; ++mf) {
                const int xb = mg * 32 + mf * 16 + q * 4;
                #pragma unroll
                for (int r = 0; r < 4; ++r) {
                    float v = acc[mf][0][r] + bb;
                    flowout[((long)b * 2 + l15) * HW + y * W + xb + r] = leakyf(v);
                }
            }
        }
    }
}

// ---------------------------------------------------------------------------
extern "C" void kernel_launch(void* const* d_in, const int* in_sizes, int n_in,
                              void* d_out, int out_size, void* d_ws, size_t ws_size,
                              hipStream_t stream)
{
    const float* tenOne    = (const float*)d_in[0];
    const float* tenTwo    = (const float*)d_in[1];
    const float* prev_flow = (const float*)d_in[2];
    const float* prev_feat = (const float*)d_in[3];
    const float* w_upflow  = (const float*)d_in[4];
    const float* b_upflow  = (const float*)d_in[5];
    const float* w_upfeat  = (const float*)d_in[6];
    const float* b_upfeat  = (const float*)d_in[7];
    const float* wc[6] = {(const float*)d_in[8],  (const float*)d_in[10], (const float*)d_in[12],
                          (const float*)d_in[14], (const float*)d_in[16], (const float*)d_in[18]};
    const float* bc[6] = {(const float*)d_in[9],  (const float*)d_in[11], (const float*)d_in[13],
                          (const float*)d_in[15], (const float*)d_in[17], (const float*)d_in[19]};

    float* flow_out = (float*)d_out;                  // (B,2,H,W)
    float* feat_out = flow_out + (long)NB * 2 * HW;   // (B,629,H,W)

    // workspace layout (bytes)
    // featn: 20 chunks x 65536 px x 32 ch x 2B = 83,886,080
    // warped_n ALIASES featn chunks 0..2 (12,582,912 B): chunks 0..2 are only
    // written by conv4/conv5, which run after corr has consumed warped_n.
    char* ws = (char*)d_ws;
    unsigned short* featn    = (unsigned short*)ws;
    unsigned short* warped_n = (unsigned short*)ws;                 // alias, see above
    float* flow4 = (float*)(ws + 83886080L);                        // 524,288
    float* up4   = (float*)(ws + 84410368L);                        // 524,288
    unsigned short* wt1 = (unsigned short*)(ws + 84934656L);        // 442,368
    unsigned short* wt2 = (unsigned short*)(ws + 85377024L);        // 737,280
    unsigned short* wt3 = (unsigned short*)(ws + 86114304L);        // 774,144
    unsigned short* wt4 = (unsigned short*)(ws + 86888448L);        // 626,688
    unsigned short* wt5 = (unsigned short*)(ws + 87515136L);        // 350,208
    unsigned short* wt6 = (unsigned short*)(ws + 87865344L);        // 184,320
    unsigned short* wts[6] = {wt1, wt2, wt3, wt4, wt5, wt6};

    const int Cout[6] = {128, 128, 96, 64, 32, 2};
    const int Cin [6] = {181, 309, 437, 533, 597, 629};
    const int NCH [6] = {6, 10, 14, 17, 19, 20};      // K chunks (Kpad/32)
    const int NFC [6] = {8, 8, 6, 4, 2, 1};           // CoPd/16
    const int c0  [6] = {448, 320, 192, 96, 32, 0};
    const int oc0 [6] = {320, 192, 96, 32, 0, 0};

    for (int i = 0; i < 6; ++i) {
        long total = (long)NCH[i] * 9 * NFC[i] * 512;
        wcvt_kernel<<<(int)((total + 255) / 256), 256, 0, stream>>>(
            wc[i], wts[i], Cout[i], Cin[i], NFC[i], total);
    }

    // upsample flow (small) + feat (split-reduce)
    upconv2_kernel<<<dim3(H, NB), W, 0, stream>>>(prev_flow, 2, 32, 64,
                                                  w_upflow, b_upflow, flow4, (long)(2 * HW));
    upconv2_split_kernel<<<dim3(H, NB), 1024, 0, stream>>>(prev_feat, 661, 32, 64,
                                                           w_upfeat, b_upfeat, up4, (long)(2 * HW));

    // pack static channels, warp, correlation
    pack_kernel<<<256, 256, 0, stream>>>(tenOne, flow4, up4, featn);
    warp_nhwc_kernel<<<512, 512, 0, stream>>>(tenTwo, flow4, warped_n);
    corr_kernel<<<512, 512, 0, stream>>>(tenOne, warped_n, featn);

    // conv chain (MFMA), 8-wave blocks
    conv_mfma<8><<<512, 512, 0, stream>>>(featn, c0[0], NCH[0], wts[0], bc[0], featn, oc0[0], nullptr);
    conv_mfma<8><<<512, 512, 0, stream>>>(featn, c0[1], NCH[1], wts[1], bc[1], featn, oc0[1], nullptr);
    conv_mfma<6><<<512, 512, 0, stream>>>(featn, c0[2], NCH[2], wts[2], bc[2], featn, oc0[2], nullptr);
    conv_mfma<4><<<512, 512, 0, stream>>>(featn, c0[3], NCH[3], wts[3], bc[3], featn, oc0[3], nullptr);
    conv_mfma<2><<<512, 512, 0, stream>>>(featn, c0[4], NCH[4], wts[4], bc[4], featn, oc0[4], nullptr);
    conv_mfma<1><<<512, 512, 0, stream>>>(featn, c0[5], NCH[5], wts[5], bc[5], featn, 0, flow_out);

    // unpack feat to fp32 NCHW output
    unpack_kernel<<<256, 256, 0, stream>>>(featn, feat_out);
}

// Round 4
// 784.019 us; speedup vs baseline: 2.4698x; 1.1500x over previous
//
#include <hip/hip_runtime.h>

#define W 128
#define H 64
#define HW 8192
#define NB 8
#define NPIX 65536              // NB*HW
#define CHSZ 2097152L           // shorts per channel-chunk: NPIX*32

typedef __attribute__((ext_vector_type(8))) short short8;
typedef __attribute__((ext_vector_type(4))) float floatx4;

__device__ __forceinline__ float leakyf(float v) { return v >= 0.f ? v : 0.1f * v; }

__device__ __forceinline__ unsigned short f2bf(float f) {
    unsigned u = __float_as_uint(f);
    u += 0x7FFF + ((u >> 16) & 1);          // RNE
    return (unsigned short)(u >> 16);
}
__device__ __forceinline__ float bf2f(unsigned short s) {
    return __uint_as_float((unsigned)s << 16);
}

// featn layout: chunked-channel NHWC. addr(c, pix) = ((c>>5)*NPIX + pix)*32 + (c&31)
// chunks 0..19 cover channels 0..639 (629 real + zero pad).
// warped_n layout: 16-ch chunks. addr(c, pix) = ((c>>4)*NPIX + pix)*16 + (c&15)

// ---------------------------------------------------------------------------
// ConvTranspose2d k=4 s=2 p=1, Cout=2, small Cin (used for prev_flow, Cin=2)
// ---------------------------------------------------------------------------
__global__ void upconv2_kernel(const float* __restrict__ in, int Cin, int Hin, int Win,
                               const float* __restrict__ w, const float* __restrict__ bias,
                               float* __restrict__ out, long obs)
{
    const int x = threadIdx.x;
    const int y = blockIdx.x;
    const int b = blockIdx.y;

    const int p = (y + 1) & 1;
    const int kyA = p, kyB = p + 2;
    const int iyA = (y + 1 - kyA) >> 1;
    const int iyB = (y + 1 - kyB) >> 1;
    const bool vyA = (iyA >= 0) && (iyA < Hin);
    const bool vyB = (iyB >= 0) && (iyB < Hin);

    const int q = (x + 1) & 1;
    const int kxA = q, kxB = q + 2;
    const int ixA = (x + 1 - kxA) >> 1;
    const int ixB = (x + 1 - kxB) >> 1;
    const bool vxA = (ixA >= 0) && (ixA < Win);
    const bool vxB = (ixB >= 0) && (ixB < Win);

    const bool mAA = vyA && vxA, mAB = vyA && vxB, mBA = vyB && vxA, mBB = vyB && vxB;
    const int oAA = iyA * Win + ixA, oAB = iyA * Win + ixB;
    const int oBA = iyB * Win + ixA, oBB = iyB * Win + ixB;
    const int wAA = kyA * 4 + kxA, wAB = kyA * 4 + kxB;
    const int wBA = kyB * 4 + kxA, wBB = kyB * 4 + kxB;

    float acc0 = bias[0];
    float acc1 = bias[1];
    const long hwin = (long)Hin * Win;
    const float* ip = in + (long)b * Cin * hwin;
    const float* wp = w;
    for (int ci = 0; ci < Cin; ++ci, ip += hwin, wp += 32) {
        float vAA = mAA ? ip[oAA] : 0.f;
        float vAB = mAB ? ip[oAB] : 0.f;
        float vBA = mBA ? ip[oBA] : 0.f;
        float vBB = mBB ? ip[oBB] : 0.f;
        acc0 += vAA * wp[wAA] + vAB * wp[wAB] + vBA * wp[wBA] + vBB * wp[wBB];
        acc1 += vAA * wp[16 + wAA] + vAB * wp[16 + wAB] + vBA * wp[16 + wBA] + vBB * wp[16 + wBB];
    }
    long o = (long)b * obs + y * W + x;
    out[o]      = acc0;
    out[o + HW] = acc1;
}

// ---------------------------------------------------------------------------
// Same transpose-conv, Cin split 8 ways within a 1024-thread block (Cin=661).
// ---------------------------------------------------------------------------
__global__ __launch_bounds__(1024) void upconv2_split_kernel(
    const float* __restrict__ in, int Cin, int Hin, int Win,
    const float* __restrict__ w, const float* __restrict__ bias,
    float* __restrict__ out, long obs)
{
    __shared__ float red[8][128][2];

    const int x = threadIdx.x & 127;
    const int s = threadIdx.x >> 7;       // split 0..7 (wave-uniform)
    const int y = blockIdx.x;
    const int b = blockIdx.y;

    const int p = (y + 1) & 1;
    const int kyA = p, kyB = p + 2;
    const int iyA = (y + 1 - kyA) >> 1;
    const int iyB = (y + 1 - kyB) >> 1;
    const bool vyA = (iyA >= 0) && (iyA < Hin);
    const bool vyB = (iyB >= 0) && (iyB < Hin);

    const int q = (x + 1) & 1;
    const int kxA = q, kxB = q + 2;
    const int ixA = (x + 1 - kxA) >> 1;
    const int ixB = (x + 1 - kxB) >> 1;
    const bool vxA = (ixA >= 0) && (ixA < Win);
    const bool vxB = (ixB >= 0) && (ixB < Win);

    const bool mAA = vyA && vxA, mAB = vyA && vxB, mBA = vyB && vxA, mBB = vyB && vxB;
    const int oAA = iyA * Win + ixA, oAB = iyA * Win + ixB;
    const int oBA = iyB * Win + ixA, oBB = iyB * Win + ixB;
    const int wAA = kyA * 4 + kxA, wAB = kyA * 4 + kxB;
    const int wBA = kyB * 4 + kxA, wBB = kyB * 4 + kxB;

    const int per = (Cin + 7) / 8;
    const int lo = s * per;
    const int hi = min(lo + per, Cin);

    float acc0 = 0.f, acc1 = 0.f;
    const long hwin = (long)Hin * Win;
    const float* ip = in + (long)b * Cin * hwin + (long)lo * hwin;
    const float* wp = w + lo * 32;
    for (int ci = lo; ci < hi; ++ci, ip += hwin, wp += 32) {
        float vAA = mAA ? ip[oAA] : 0.f;
        float vAB = mAB ? ip[oAB] : 0.f;
        float vBA = mBA ? ip[oBA] : 0.f;
        float vBB = mBB ? ip[oBB] : 0.f;
        acc0 += vAA * wp[wAA] + vAB * wp[wAB] + vBA * wp[wBA] + vBB * wp[wBB];
        acc1 += vAA * wp[16 + wAA] + vAB * wp[16 + wAB] + vBA * wp[16 + wBA] + vBB * wp[16 + wBB];
    }
    red[s][x][0] = acc0;
    red[s][x][1] = acc1;
    __syncthreads();
    if (s == 0) {
        float a0 = bias[0], a1 = bias[1];
        #pragma unroll
        for (int t = 0; t < 8; ++t) { a0 += red[t][x][0]; a1 += red[t][x][1]; }
        long o = (long)b * obs + y * W + x;
        out[o]      = a0;
        out[o + HW] = a1;
    }
}

// ---------------------------------------------------------------------------
// Bilinear warp (zeros padding) -> warped_n 16-ch-chunked bf16.
// ---------------------------------------------------------------------------
__global__ __launch_bounds__(512) void warp_nhwc_kernel(
    const float* __restrict__ tenTwo, const float* __restrict__ flow4,
    unsigned short* __restrict__ warped_n)
{
    __shared__ unsigned short tile[128 * 98];   // pitch 98 shorts: conflict-free b16 stores

    const int x   = threadIdx.x & 127;
    const int sub = threadIdx.x >> 7;           // 0..3, 24 channels each
    const int row = blockIdx.x;                 // b*H + y
    const int b = row >> 6;
    const int y = row & 63;

    const long fb = (long)b * 2 * HW + y * W + x;
    const float px = (float)x + 1.25f * flow4[fb];
    const float py = (float)y + 1.25f * flow4[fb + HW];

    const float x0f = floorf(px), y0f = floorf(py);
    const float wx = px - x0f, wy = py - y0f;
    const int x0 = (int)x0f, y0 = (int)y0f;
    const int x1 = x0 + 1,   y1 = y0 + 1;

    const bool vx0 = (x0 >= 0) && (x0 < W), vx1 = (x1 >= 0) && (x1 < W);
    const bool vy0 = (y0 >= 0) && (y0 < H), vy1 = (y1 >= 0) && (y1 < H);
    const int cx0 = min(max(x0, 0), W - 1), cx1 = min(max(x1, 0), W - 1);
    const int cy0 = min(max(y0, 0), H - 1), cy1 = min(max(y1, 0), H - 1);

    const float w00 = (1.f - wy) * (1.f - wx) * ((vy0 && vx0) ? 1.f : 0.f);
    const float w01 = (1.f - wy) * wx         * ((vy0 && vx1) ? 1.f : 0.f);
    const float w10 = wy * (1.f - wx)         * ((vy1 && vx0) ? 1.f : 0.f);
    const float w11 = wy * wx                 * ((vy1 && vx1) ? 1.f : 0.f);

    const int o00 = cy0 * W + cx0, o01 = cy0 * W + cx1;
    const int o10 = cy1 * W + cx0, o11 = cy1 * W + cx1;

    for (int i = 0; i < 24; ++i) {
        const int c = sub * 24 + i;
        const float* pch = tenTwo + (long)(b * 96 + c) * HW;
        const float v = pch[o00] * w00 + pch[o01] * w01 + pch[o10] * w10 + pch[o11] * w11;
        tile[x * 98 + c] = f2bf(v);
    }
    __syncthreads();

    // write out 128 px x 96 ch = 1536 uint4 into 16-ch-chunked layout
    const long pixbase = (long)row * 128;
    for (int u = threadIdx.x; u < 1536; u += 512) {
        const int pxi = u / 12;
        const int cc = u - pxi * 12;            // 8-ch group 0..11
        const unsigned short* tp = tile + pxi * 98 + cc * 8;
        uint4 v;
        v.x = *(const unsigned*)(tp + 0);
        v.y = *(const unsigned*)(tp + 2);
        v.z = *(const unsigned*)(tp + 4);
        v.w = *(const unsigned*)(tp + 6);
        *(uint4*)(warped_n + ((long)(cc >> 1) * NPIX + pixbase + pxi) * 16 + (cc & 1) * 8) = v;
    }
}

// ---------------------------------------------------------------------------
// Cost volume, LDS-staged. Block = 512 thr = 4 tap-groups x 128 px (one row).
// 6 channel-group passes: stage 9x136x16ch warped tile in LDS (zeros OOB),
// taps read LDS. acc[21] in registers; output transposed through LDS and
// written as full 64B lines into feat chunks 14..16 (channels 448..543:
// vol 448..528 + tenOne ch0..14 at 529..543).
// ---------------------------------------------------------------------------
__global__ __launch_bounds__(512) void corr_kernel(
    const float* __restrict__ tenOne, const unsigned short* __restrict__ warped_n,
    unsigned short* __restrict__ featn)
{
    __shared__ unsigned short smem[19584];   // union: warped tile (39168B) / out tile [96][132]

    const int tid = threadIdx.x;
    const int x  = tid & 127;
    const int kg = tid >> 7;             // 0..3 (wave-uniform)
    const int row = blockIdx.x;          // b*H + y
    const int b = row >> 6;
    const int y = row & 63;

    float acc[21];
    #pragma unroll
    for (int i = 0; i < 21; ++i) acc[i] = 0.f;

    const int k0 = kg * 21;

    for (int cg = 0; cg < 6; ++cg) {
        // my 16 tenOne channels (fp32, coalesced, stride HW)
        float one_c[16];
        const float* op = tenOne + ((long)b * 96 + cg * 16) * HW + y * W + x;
        #pragma unroll
        for (int j = 0; j < 16; ++j) one_c[j] = op[(long)j * HW];

        if (cg) __syncthreads();
        // stage warped tile: 9 rows x 136 px x 16 ch as two 8-ch planes
        for (int u = tid; u < 2448; u += 512) {
            const int sub = u & 1;
            const int pr = u >> 1;            // 0..1223
            const int r = pr / 136;
            const int xx = pr - r * 136;
            const int gy = y + r - 4, gx = xx - 4;
            uint4 v = make_uint4(0u, 0u, 0u, 0u);
            if (gy >= 0 && gy < H && gx >= 0 && gx < W)
                v = *(const uint4*)(warped_n + ((long)cg * NPIX + (b * H + gy) * W + gx) * 16 + sub * 8);
            *(uint4*)&smem[((sub * 9 + r) * 136 + xx) * 8] = v;
        }
        __syncthreads();

        #pragma unroll
        for (int i = 0; i < 21; ++i) {
            const int k = min(k0 + i, 80);   // kg3 tail clamps (dupes discarded)
            const int ry = k / 9;            // dy+4
            const int rx = x + (k - ry * 9); // x+dx+4
            const uint4 va = *(const uint4*)&smem[(ry * 136 + rx) * 8];
            const uint4 vb = *(const uint4*)&smem[((9 + ry) * 136 + rx) * 8];
            const unsigned ua[4] = {va.x, va.y, va.z, va.w};
            const unsigned ub[4] = {vb.x, vb.y, vb.z, vb.w};
            float s = 0.f;
            #pragma unroll
            for (int e = 0; e < 4; ++e) {
                s += one_c[2 * e]     * __uint_as_float(ua[e] << 16)
                   + one_c[2 * e + 1] * __uint_as_float(ua[e] & 0xffff0000u)
                   + one_c[8 + 2 * e]     * __uint_as_float(ub[e] << 16)
                   + one_c[8 + 2 * e + 1] * __uint_as_float(ub[e] & 0xffff0000u);
            }
            acc[i] += s;
        }
    }

    __syncthreads();   // taps done everywhere; reuse smem as out tile [96][132]

    #pragma unroll
    for (int i = 0; i < 21; ++i) {
        const int k = k0 + i;
        if (k <= 80) smem[k * 132 + x] = f2bf(leakyf(acc[i] * (1.f / 96.f)));
    }
    if (kg == 0) {   // rows 81..95 = tenOne ch 0..14 (channels 529..543)
        const float* op0 = tenOne + (long)b * 96 * HW + y * W + x;
        #pragma unroll
        for (int j = 0; j < 15; ++j)
            smem[(81 + j) * 132 + x] = f2bf(op0[(long)j * HW]);
    }
    __syncthreads();

    // coalesced writes: chunks 14..16, full 64B per pixel per chunk
    #pragma unroll
    for (int it = 0; it < 3; ++it) {
        const int u = tid + it * 512;        // 0..1535
        const int sub = u & 3;
        const int px = (u >> 2) & 127;
        const int cc = u >> 9;               // 0..2
        const int t0 = cc * 32 + sub * 8;
        unsigned short bufo[8];
        #pragma unroll
        for (int j = 0; j < 8; ++j) bufo[j] = smem[(t0 + j) * 132 + px];
        *(uint4*)(featn + ((long)(14 + cc) * NPIX + (long)row * 128 + px) * 32 + sub * 8) = *(const uint4*)bufo;
    }
}

// ---------------------------------------------------------------------------
// Pack tenOne ch15..95 / flow / upfeat into featn bf16 channels 544..639.
// (448..543 are written by corr_kernel; 629..639 zero pad.)
// ---------------------------------------------------------------------------
__global__ void pack_kernel(const float* __restrict__ one, const float* __restrict__ flow4,
                            const float* __restrict__ up4, unsigned short* __restrict__ featn)
{
    const long t = (long)blockIdx.x * 256 + threadIdx.x;    // pixel 0..65535
    const long b = t >> 13;
    const long p = t & (HW - 1);
    unsigned short buf[8];
    for (int cc = 0; cc < 12; ++cc) {
        const int cbase = 544 + cc * 8;
        #pragma unroll
        for (int j = 0; j < 8; ++j) {
            const int c = cbase + j;
            float v;
            if (c < 625)      v = one[(b * 96 + (c - 529)) * HW + p];
            else if (c < 627) v = flow4[(b * 2 + (c - 625)) * HW + p];
            else if (c < 629) v = up4[(b * 2 + (c - 627)) * HW + p];
            else              v = 0.f;
            buf[j] = f2bf(v);
        }
        *(uint4*)(featn + ((long)(cbase >> 5) * NPIX + t) * 32 + (cbase & 31)) = *(const uint4*)buf;
    }
}

// ---------------------------------------------------------------------------
// feat_nhwc (chunked) bf16 -> d_out feat region fp32 NCHW (B,629,H,W)
// ---------------------------------------------------------------------------
__global__ void unpack_kernel(const unsigned short* __restrict__ featn, float* __restrict__ out)
{
    const long t = (long)blockIdx.x * 256 + threadIdx.x;    // pixel
    const long b = t >> 13;
    const long p = t & (HW - 1);
    const unsigned short* f = featn + t * 32;
    float* ob = out + b * 629L * HW + p;
    for (int cc = 0; cc < 20; ++cc) {
        const unsigned short* fc = f + (long)cc * CHSZ;
        #pragma unroll
        for (int g = 0; g < 4; ++g) {
            uint4 v = *(const uint4*)(fc + g * 8);
            unsigned short s[8];
            *(uint4*)s = v;
            #pragma unroll
            for (int j = 0; j < 8; ++j) {
                const int c = cc * 32 + g * 8 + j;
                if (c < 629) ob[(long)c * HW] = bf2f(s[j]);
            }
        }
    }
}

// ---------------------------------------------------------------------------
// Weight convert: fp32 OIHW -> bf16 fragment-ordered [kc][tap][nf][lane][8],
// so a wave's B-fragment load is 1KB fully contiguous.
// lane = q*16 + l15 holds co = nf*16+l15, ci = kc*32 + q*8 + j.
// ---------------------------------------------------------------------------
__global__ void wcvt_kernel(const float* __restrict__ w, unsigned short* __restrict__ wt,
                            int Cout, int Cin, int NFC, long total)
{
    const long t = (long)blockIdx.x * 256 + threadIdx.x;
    if (t >= total) return;
    const int j    = (int)(t & 7);
    const int lane = (int)((t >> 3) & 63);
    long r = t >> 9;
    const int nf  = (int)(r % NFC);  r /= NFC;
    const int tap = (int)(r % 9);
    const int kc  = (int)(r / 9);
    const int l15 = lane & 15, q = lane >> 4;
    const int co = nf * 16 + l15;
    const int ci = kc * 32 + q * 8 + j;
    float v = 0.f;
    if (co < Cout && ci < Cin) v = w[((long)co * Cin + ci) * 9 + tap];
    wt[t] = f2bf(v);
}

// ---------------------------------------------------------------------------
// Implicit-GEMM 3x3 conv, bf16 MFMA 16x16x32, fp32 accum.
// 8-wave blocks (512 thr): wave = (mg = M-tile 32px, nh = N-half).
// NF split across wave pairs -> same weight traffic as 4-wave, 2x TLP.
// LDS double-buffered -> ONE barrier per K-chunk; reg prefetch depth = chunk.
// ---------------------------------------------------------------------------
template<int NFT>
__global__ __launch_bounds__(512, 4) void conv_mfma(
    const unsigned short* __restrict__ featn, int c0, int nchunks,
    const unsigned short* __restrict__ wt, const float* __restrict__ bias,
    unsigned short* __restrict__ outf, int oc0, float* __restrict__ flowout)
{
    constexpr int NFW = (NFT + 1) / 2;          // frags per wave (N-split 2)
    __shared__ unsigned short tile[2][3 * 130 * 40];   // 62,400 B

    const int row = blockIdx.x;          // b*H + y
    const int b = row >> 6;
    const int y = row & 63;
    const int tid = threadIdx.x;
    const int lane = tid & 63;
    const int wave = tid >> 6;
    const int mg = wave & 3;             // 32-px M-tile group
    const int nh = wave >> 2;            // N half (0/1)
    const int l15 = lane & 15;
    const int q = lane >> 4;
    const bool active = (nh * NFW) < NFT;   // NFT=1: nh=1 waves stage only

    // staging descriptors: 1560 uint4 units (3 rows x 130 px x 4 subs of 16B)
    int gofs[4];
    int lofs[4];
    #pragma unroll
    for (int it = 0; it < 4; ++it) {
        const int u = tid + it * 512;
        const int pr = u >> 2;           // pixel unit 0..389
        const int sub = u & 3;
        const int r = (pr >= 260) ? 2 : (pr >= 130 ? 1 : 0);
        const int xx = pr - r * 130;
        const int gy = y + r - 1, gx = xx - 1;
        const bool inu = (u < 1560);
        const bool inb = inu && (gy >= 0) && (gy < H) && (gx >= 0) && (gx < W);
        gofs[it] = inb ? (((b * H + gy) * W + gx) * 32 + sub * 8) : -1;
        lofs[it] = inu ? (pr * 40 + sub * 8) : -1;
    }

    floatx4 acc[2][NFW];
    #pragma unroll
    for (int mf = 0; mf < 2; ++mf)
        #pragma unroll
        for (int nf = 0; nf < NFW; ++nf)
            acc[mf][nf] = (floatx4){0.f, 0.f, 0.f, 0.f};

    const unsigned short* fb = featn + (long)(c0 >> 5) * CHSZ;   // chunk base
    const unsigned short* wlane = wt + lane * 8;

    // prologue: load chunk 0, stage into buf 0, issue chunk 1 loads
    uint4 rg[4];
    #pragma unroll
    for (int it = 0; it < 4; ++it)
        rg[it] = (gofs[it] >= 0) ? *(const uint4*)(fb + gofs[it]) : make_uint4(0u, 0u, 0u, 0u);
    #pragma unroll
    for (int it = 0; it < 4; ++it)
        if (lofs[it] >= 0) *(uint4*)&tile[0][lofs[it]] = rg[it];
    if (nchunks > 1) {
        const unsigned short* fn = fb + CHSZ;
        #pragma unroll
        for (int it = 0; it < 4; ++it)
            rg[it] = (gofs[it] >= 0) ? *(const uint4*)(fn + gofs[it]) : make_uint4(0u, 0u, 0u, 0u);
    }
    __syncthreads();

    for (int kc = 0; kc < nchunks; ++kc) {
        const int cur = kc & 1;

        // stage chunk kc+1 into the other buffer, then issue chunk kc+2 loads.
        if (kc + 1 < nchunks) {
            #pragma unroll
            for (int it = 0; it < 4; ++it)
                if (lofs[it] >= 0) *(uint4*)&tile[cur ^ 1][lofs[it]] = rg[it];
        }
        if (kc + 2 < nchunks) {
            const unsigned short* fn = fb + (long)(kc + 2) * CHSZ;
            #pragma unroll
            for (int it = 0; it < 4; ++it)
                rg[it] = (gofs[it] >= 0) ? *(const uint4*)(fn + gofs[it]) : make_uint4(0u, 0u, 0u, 0u);
        }

        if (active) {
            #pragma unroll
            for (int ky = 0; ky < 3; ++ky) {
                #pragma unroll
                for (int kx = 0; kx < 3; ++kx) {
                    const int tap = ky * 3 + kx;
                    const short8 a0 = *(const short8*)&tile[cur][(ky * 130 + mg * 32 + l15 + kx) * 40 + q * 8];
                    const short8 a1 = *(const short8*)&tile[cur][(ky * 130 + mg * 32 + 16 + l15 + kx) * 40 + q * 8];
                    const unsigned short* wb = wlane + ((long)((kc * 9 + tap) * NFT + nh * NFW) << 9);
                    #pragma unroll
                    for (int nf = 0; nf < NFW; ++nf) {
                        const short8 bf = *(const short8*)(wb + ((long)nf << 9));
                        acc[0][nf] = __builtin_amdgcn_mfma_f32_16x16x32_bf16(a0, bf, acc[0][nf], 0, 0, 0);
                        acc[1][nf] = __builtin_amdgcn_mfma_f32_16x16x32_bf16(a1, bf, acc[1][nf], 0, 0, 0);
                    }
                }
            }
        }
        __syncthreads();
    }

    if (flowout == nullptr) {
        if (active) {
            float bv[NFW];
            #pragma unroll
            for (int nf = 0; nf < NFW; ++nf) bv[nf] = bias[(nh * NFW + nf) * 16 + l15];
            const int cchunk0 = oc0 >> 5;
            #pragma unroll
            for (int mf = 0; mf < 2; ++mf) {
                const int xb = mg * 32 + mf * 16 + q * 4;
                #pragma unroll
                for (int r = 0; r < 4; ++r) {
                    const long pixo = (long)row * W + xb + r;
                    #pragma unroll
                    for (int nf = 0; nf < NFW; ++nf) {
                        const int nfg = nh * NFW + nf;
                        float v = acc[mf][nf][r] + bv[nf];
                        const long a = ((long)(cchunk0 + (nfg >> 1)) * NPIX + pixo) * 32 + (nfg & 1) * 16 + l15;
                        outf[a] = f2bf(leakyf(v));
                    }
                }
            }
        }
    } else {
        if (active && l15 < 2) {
            const float bb = bias[l15];
            #pragma unroll
            for (int mf = 0; mf < 2; ++mf) {
                const int xb = mg * 32 + mf * 16 + q * 4;
                #pragma unroll
                for (int r = 0; r < 4; ++r) {
                    float v = acc[mf][0][r] + bb;
                    flowout[((long)b * 2 + l15) * HW + y * W + xb + r] = leakyf(v);
                }
            }
        }
    }
}

// ---------------------------------------------------------------------------
extern "C" void kernel_launch(void* const* d_in, const int* in_sizes, int n_in,
                              void* d_out, int out_size, void* d_ws, size_t ws_size,
                              hipStream_t stream)
{
    const float* tenOne    = (const float*)d_in[0];
    const float* tenTwo    = (const float*)d_in[1];
    const float* prev_flow = (const float*)d_in[2];
    const float* prev_feat = (const float*)d_in[3];
    const float* w_upflow  = (const float*)d_in[4];
    const float* b_upflow  = (const float*)d_in[5];
    const float* w_upfeat  = (const float*)d_in[6];
    const float* b_upfeat  = (const float*)d_in[7];
    const float* wc[6] = {(const float*)d_in[8],  (const float*)d_in[10], (const float*)d_in[12],
                          (const float*)d_in[14], (const float*)d_in[16], (const float*)d_in[18]};
    const float* bc[6] = {(const float*)d_in[9],  (const float*)d_in[11], (const float*)d_in[13],
                          (const float*)d_in[15], (const float*)d_in[17], (const float*)d_in[19]};

    float* flow_out = (float*)d_out;                  // (B,2,H,W)
    float* feat_out = flow_out + (long)NB * 2 * HW;   // (B,629,H,W)

    // workspace layout (bytes)
    // featn: 20 chunks x 65536 px x 32 ch x 2B = 83,886,080
    // warped_n ALIASES featn chunks 0..2 (12,582,912 B): chunks 0..2 are only
    // written by conv4/conv5, which run after corr has consumed warped_n.
    char* ws = (char*)d_ws;
    unsigned short* featn    = (unsigned short*)ws;
    unsigned short* warped_n = (unsigned short*)ws;                 // alias, see above
    float* flow4 = (float*)(ws + 83886080L);                        // 524,288
    float* up4   = (float*)(ws + 84410368L);                        // 524,288
    unsigned short* wt1 = (unsigned short*)(ws + 84934656L);        // 442,368
    unsigned short* wt2 = (unsigned short*)(ws + 85377024L);        // 737,280
    unsigned short* wt3 = (unsigned short*)(ws + 86114304L);        // 774,144
    unsigned short* wt4 = (unsigned short*)(ws + 86888448L);        // 626,688
    unsigned short* wt5 = (unsigned short*)(ws + 87515136L);        // 350,208
    unsigned short* wt6 = (unsigned short*)(ws + 87865344L);        // 184,320
    unsigned short* wts[6] = {wt1, wt2, wt3, wt4, wt5, wt6};

    const int Cout[6] = {128, 128, 96, 64, 32, 2};
    const int Cin [6] = {181, 309, 437, 533, 597, 629};
    const int NCH [6] = {6, 10, 14, 17, 19, 20};      // K chunks (Kpad/32)
    const int NFC [6] = {8, 8, 6, 4, 2, 1};           // CoPd/16
    const int c0  [6] = {448, 320, 192, 96, 32, 0};
    const int oc0 [6] = {320, 192, 96, 32, 0, 0};

    for (int i = 0; i < 6; ++i) {
        long total = (long)NCH[i] * 9 * NFC[i] * 512;
        wcvt_kernel<<<(int)((total + 255) / 256), 256, 0, stream>>>(
            wc[i], wts[i], Cout[i], Cin[i], NFC[i], total);
    }

    // upsample flow (small) + feat (split-reduce)
    upconv2_kernel<<<dim3(H, NB), W, 0, stream>>>(prev_flow, 2, 32, 64,
                                                  w_upflow, b_upflow, flow4, (long)(2 * HW));
    upconv2_split_kernel<<<dim3(H, NB), 1024, 0, stream>>>(prev_feat, 661, 32, 64,
                                                           w_upfeat, b_upfeat, up4, (long)(2 * HW));

    // pack static channels, warp, correlation
    pack_kernel<<<256, 256, 0, stream>>>(tenOne, flow4, up4, featn);
    warp_nhwc_kernel<<<512, 512, 0, stream>>>(tenTwo, flow4, warped_n);
    corr_kernel<<<512, 512, 0, stream>>>(tenOne, warped_n, featn);

    // conv chain (MFMA), 8-wave blocks
    conv_mfma<8><<<512, 512, 0, stream>>>(featn, c0[0], NCH[0], wts[0], bc[0], featn, oc0[0], nullptr);
    conv_mfma<8><<<512, 512, 0, stream>>>(featn, c0[1], NCH[1], wts[1], bc[1], featn, oc0[1], nullptr);
    conv_mfma<6><<<512, 512, 0, stream>>>(featn, c0[2], NCH[2], wts[2], bc[2], featn, oc0[2], nullptr);
    conv_mfma<4><<<512, 512, 0, stream>>>(featn, c0[3], NCH[3], wts[3], bc[3], featn, oc0[3], nullptr);
    conv_mfma<2><<<512, 512, 0, stream>>>(featn, c0[4], NCH[4], wts[4], bc[4], featn, oc0[4], nullptr);
    conv_mfma<1><<<512, 512, 0, stream>>>(featn, c0[5], NCH[5], wts[5], bc[5], featn, 0, flow_out);

    // unpack feat to fp32 NCHW output
    unpack_kernel<<<256, 256, 0, stream>>>(featn, feat_out);
}